// Round 10
// baseline (344.014 us; speedup 1.0000x reference)
//
#include <hip/hip_runtime.h>
#include <hip/hip_bf16.h>
#include <cstddef>

// ---------------------------------------------------------------------------
// GCN variational encoder: N nodes, E edges, H=128 hidden, C=64 out.
// A(HW) = (AH)W lets each layer gather in the narrow domain.
// Gathers: per-VMEM-instruction packed; 128-wide gather sits at the random
// 64B-line L2-fill fabric ceiling (~186MB @ ~3.8TB/s) -- accepted floor.
// CSR build: atomic-free 3-phase (per-tile hist stores -> bucket+tile scan
// -> single-pass LDS-ranked scatter -> per-bucket sort w/ rptr/dinv/xd).
// Heads: gather and 64->128 matmul fused (g3 row broadcast via shfl,
// {Wmu|Wls} interleaved in LDS) -- no intermediate buffer.
// ---------------------------------------------------------------------------

// ---- CSR pipeline (bucket = dst>>8; requires n <= 65536) ----

// per-tile bucket histogram, plain stores
__global__ __launch_bounds__(256) void k_hist(const int* __restrict__ dst,
                                              int* __restrict__ hist_g, int e) {
    __shared__ int h[256];
    const int tid = threadIdx.x;
    h[tid] = 0;
    __syncthreads();
    const int e0 = blockIdx.x * 4096;
    const int e1 = min(e0 + 4096, e);
    for (int j = e0 + tid; j < e1; j += 256) atomicAdd(&h[dst[j] >> 8], 1);
    __syncthreads();
    hist_g[blockIdx.x * 256 + tid] = h[tid];
}

// single block: per-bucket scan over tiles -> tbase; bucket scan -> boff[257]
__global__ __launch_bounds__(256) void k_scan2(const int* __restrict__ hist_g,
                                               int* __restrict__ tbase,
                                               int* __restrict__ boff, int ntile) {
    const int b = threadIdx.x;
    int acc = 0;
    for (int t = 0; t < ntile; ++t) {
        int v = hist_g[t * 256 + b];
        tbase[t * 256 + b] = acc;
        acc += v;
    }
    __shared__ int wsum[4];
    const int lane = b & 63, wv = b >> 6;
    int v = acc;
#pragma unroll
    for (int d = 1; d < 64; d <<= 1) {
        int w = __shfl_up(v, d, 64);
        if (lane >= d) v += w;
    }
    if (lane == 63) wsum[wv] = v;
    __syncthreads();
    int woff = 0;
    for (int w = 0; w < wv; ++w) woff += wsum[w];
    int excl = woff + v - acc;
    boff[b] = excl;
    if (b == 255) boff[256] = excl + acc;
}

// single-pass scatter: packed (dlocal<<16 | src) at boff[b]+tbase[tile][b]+rank
__global__ __launch_bounds__(256) void k_binA3(const int* __restrict__ src,
                                               const int* __restrict__ dst,
                                               const int* __restrict__ boff,
                                               const int* __restrict__ tbase,
                                               int* __restrict__ packed, int e) {
    __shared__ int hist[256];
    __shared__ int base[256];
    const int tid = threadIdx.x;
    const int e0 = blockIdx.x * 4096;
    const int e1 = min(e0 + 4096, e);
    hist[tid] = 0;
    base[tid] = boff[tid] + tbase[blockIdx.x * 256 + tid];
    __syncthreads();
    for (int j = e0 + tid; j < e1; j += 256) {
        int d = dst[j];
        int b = d >> 8;
        int r = atomicAdd(&hist[b], 1);
        packed[base[b] + r] = ((d & 255) << 16) | src[j];
    }
}

// per bucket: node hist + in-block scan -> rptr/dinv/xd; LDS sort -> col
#define BCAP 6144
__global__ __launch_bounds__(256) void k_binB2(const int* __restrict__ packed,
                                               const int* __restrict__ boff,
                                               const int* __restrict__ x,
                                               int* __restrict__ rptr,
                                               float* __restrict__ dinv,
                                               int2* __restrict__ xd,
                                               int* __restrict__ col,
                                               int n) {
    __shared__ int hist[256];
    __shared__ int cur[256];
    __shared__ int wsum[4];
    __shared__ int buf[BCAP];
    const int tid = threadIdx.x;
    const int lane = tid & 63, wv = tid >> 6;
    const int node0 = blockIdx.x << 8;
    const int node1 = min(node0 + 256, n);
    const int ebeg = boff[blockIdx.x];
    const int eend = boff[blockIdx.x + 1];
    const int cnt = eend - ebeg;

    hist[tid] = 0;
    __syncthreads();
    for (int j = tid; j < cnt; j += 256) atomicAdd(&hist[packed[ebeg + j] >> 16], 1);
    __syncthreads();
    const int deg = hist[tid];
    int v = deg;
#pragma unroll
    for (int d = 1; d < 64; d <<= 1) {
        int w = __shfl_up(v, d, 64);
        if (lane >= d) v += w;
    }
    if (lane == 63) wsum[wv] = v;
    __syncthreads();
    int woff = 0;
    for (int w = 0; w < wv; ++w) woff += wsum[w];
    const int excl = woff + v - deg;
    cur[tid] = excl;
    const int node = node0 + tid;
    if (node < node1) {
        rptr[node] = ebeg + excl;
        float dv = 1.0f / sqrtf((float)(deg + 1));
        dinv[node] = dv;
        xd[node] = make_int2(x[node], __float_as_int(dv));
    }
    if (node1 == n && tid == 0) rptr[n] = eend;
    __syncthreads();

    if (cnt <= BCAP) {
        for (int j = tid; j < cnt; j += 256) {
            int p = packed[ebeg + j];
            int pos = atomicAdd(&cur[p >> 16], 1);
            buf[pos] = p & 0xffff;
        }
        __syncthreads();
        for (int j = tid; j < cnt; j += 256) col[ebeg + j] = buf[j];
    } else {
        for (int j = tid; j < cnt; j += 256) {
            int p = packed[ebeg + j];
            int pos = atomicAdd(&cur[p >> 16], 1);
            col[ebeg + pos] = p & 0xffff;
        }
    }
}

// fused weight prep: blocks [0,nsm): M = embW @ W1 (2 rows/block);
// blocks [nsm, nsm+16): Wpair[k*64+c] = {Wmu[k][c], Wls[k][c]}
__global__ __launch_bounds__(256) void k_prepW(const float* __restrict__ embW,
                                               const float* __restrict__ W1,
                                               const float* __restrict__ Wmu,
                                               const float* __restrict__ Wls,
                                               float* __restrict__ M,
                                               float2* __restrict__ Wpair,
                                               int V, int nsm) {
    if ((int)blockIdx.x < nsm) {
        const int r = blockIdx.x * 2 + (threadIdx.x >> 7);
        const int c = threadIdx.x & 127;
        if (r >= V) return;
        float a0 = 0.f, a1 = 0.f;
        const float* er = embW + (size_t)r * 128;
#pragma unroll 4
        for (int k = 0; k < 128; k += 2) {
            a0 = fmaf(er[k], W1[(size_t)k * 128 + c], a0);
            a1 = fmaf(er[k + 1], W1[(size_t)(k + 1) * 128 + c], a1);
        }
        M[(size_t)r * 128 + c] = a0 + a1;
    } else {
        int i = (blockIdx.x - nsm) * 256 + threadIdx.x;
        if (i < 64 * 64) Wpair[i] = make_float2(Wmu[i], Wls[i]);
    }
}

// layer-1 gather: M table (V<=32 rows x 128) in LDS; per edge read packed
// xd[s]={x,dinv} (8B, L2-resident) and accumulate dinv * M[x].
__global__ __launch_bounds__(256) void k_gather_l1(const float* __restrict__ M,
                                                   const int* __restrict__ rptr,
                                                   const int* __restrict__ col,
                                                   const int2* __restrict__ xd,
                                                   const float* __restrict__ b,
                                                   float* __restrict__ out,
                                                   int n, int V) {
    __shared__ float sh[32 * 128];
    for (int f = threadIdx.x; f < V * 32; f += 256)
        ((float4*)sh)[f] = ((const float4*)M)[f];
    __syncthreads();

    const int wave = threadIdx.x >> 6;
    const int lane = threadIdx.x & 63;
    const int node = blockIdx.x * 4 + wave;
    if (node >= n) return;
    const int beg = rptr[node], end = rptr[node + 1];
    int j = beg;

    float ax0 = 0.f, ay0 = 0.f, ax1 = 0.f, ay1 = 0.f;
    const int lo = 2 * lane;
    if (end - beg >= 8) {
        int s[8];
#pragma unroll
        for (int u = 0; u < 8; ++u) s[u] = col[j + u];
        j += 8;
        while (true) {
            int2 p[8];
#pragma unroll
            for (int u = 0; u < 8; ++u) p[u] = xd[s[u]];
            const bool more = (j + 8 <= end);
            int sn[8];
            if (more) {
#pragma unroll
                for (int u = 0; u < 8; ++u) sn[u] = col[j + u];
            }
#pragma unroll
            for (int u = 0; u < 8; ++u) {
                float dv = __int_as_float(p[u].y);
                float2 v = *(const float2*)&sh[p[u].x * 128 + lo];
                if (u & 1) { ax1 = fmaf(dv, v.x, ax1); ay1 = fmaf(dv, v.y, ay1); }
                else       { ax0 = fmaf(dv, v.x, ax0); ay0 = fmaf(dv, v.y, ay0); }
            }
            if (!more) break;
#pragma unroll
            for (int u = 0; u < 8; ++u) s[u] = sn[u];
            j += 8;
        }
    }
    for (; j < end; ++j) {
        int2 p = xd[col[j]];
        float dv = __int_as_float(p.y);
        float2 v = *(const float2*)&sh[p.x * 128 + lo];
        ax0 = fmaf(dv, v.x, ax0); ay0 = fmaf(dv, v.y, ay0);
    }
    int2 pn = xd[node];
    float dn = __int_as_float(pn.y);
    float2 sv = *(const float2*)&sh[pn.x * 128 + lo];
    float2 bb = ((const float2*)b)[lane];
    float ox = (ax0 + ax1 + dn * sv.x) * dn + bb.x;
    float oy = (ay0 + ay1 + dn * sv.y) * dn + bb.y;
    ((float2*)out)[(size_t)node * 64 + lane] = {ox, oy};
}

// out[r][c] = dinv[r] * sum_k act(in[r][k]) * W[k][c]
// BM=128, KC=32; 256 threads; per-thread 8 rows x CT*4 cols register tile.
template <int K, int COUT, bool RELU>
__global__ __launch_bounds__(256) void k_matmul(const float* __restrict__ in,
                                                const float* __restrict__ W,
                                                const float* __restrict__ dinv,
                                                float* __restrict__ out, int n) {
    constexpr int BM = 128, KC = 32, LDI = KC + 4;
    constexpr int CT = COUT / 16;
    __shared__ float sIn[BM * LDI];
    __shared__ float sW[KC * COUT];

    const int tid = threadIdx.x;
    const int row0 = blockIdx.x * BM;
    const int tc = tid & 15;
    const int tr = tid >> 4;

    float acc[8][CT];
#pragma unroll
    for (int j = 0; j < 8; ++j)
#pragma unroll
        for (int c = 0; c < CT; ++c) acc[j][c] = 0.f;

    const int sr = tid >> 3;
    const int sk = (tid & 7) * 4;

    for (int kc = 0; kc < K; kc += KC) {
#pragma unroll
        for (int p = 0; p < 4; ++p) {
            int rr = p * 32 + sr;
            int gr = row0 + rr;
            float4 v = {0.f, 0.f, 0.f, 0.f};
            if (gr < n) v = *(const float4*)&in[(size_t)gr * K + kc + sk];
            if (RELU) {
                v.x = fmaxf(v.x, 0.f); v.y = fmaxf(v.y, 0.f);
                v.z = fmaxf(v.z, 0.f); v.w = fmaxf(v.w, 0.f);
            }
            *(float4*)&sIn[rr * LDI + sk] = v;
        }
        for (int f4 = tid; f4 < KC * COUT / 4; f4 += 256)
            *(float4*)&sW[f4 * 4] = *(const float4*)&W[(size_t)kc * COUT + f4 * 4];
        __syncthreads();

        for (int kk = 0; kk < KC; kk += 4) {
            float4 a[8];
#pragma unroll
            for (int j = 0; j < 8; ++j)
                a[j] = *(const float4*)&sIn[(tr * 8 + j) * LDI + kk];
#pragma unroll
            for (int t = 0; t < 4; ++t) {
                float4 w0 = *(const float4*)&sW[(kk + t) * COUT + tc * 4];
                float4 w1;
                if constexpr (CT == 8)
                    w1 = *(const float4*)&sW[(kk + t) * COUT + COUT / 2 + tc * 4];
#pragma unroll
                for (int j = 0; j < 8; ++j) {
                    float av = (t == 0) ? a[j].x : (t == 1) ? a[j].y
                             : (t == 2) ? a[j].z : a[j].w;
                    acc[j][0] = fmaf(av, w0.x, acc[j][0]);
                    acc[j][1] = fmaf(av, w0.y, acc[j][1]);
                    acc[j][2] = fmaf(av, w0.z, acc[j][2]);
                    acc[j][3] = fmaf(av, w0.w, acc[j][3]);
                    if constexpr (CT == 8) {
                        acc[j][4] = fmaf(av, w1.x, acc[j][4]);
                        acc[j][5] = fmaf(av, w1.y, acc[j][5]);
                        acc[j][6] = fmaf(av, w1.z, acc[j][6]);
                        acc[j][7] = fmaf(av, w1.w, acc[j][7]);
                    }
                }
            }
        }
        __syncthreads();
    }

#pragma unroll
    for (int j = 0; j < 8; ++j) {
        int gr = row0 + tr * 8 + j;
        if (gr < n) {
            float dv = dinv[gr];
            float4 o0 = {acc[j][0] * dv, acc[j][1] * dv, acc[j][2] * dv, acc[j][3] * dv};
            *(float4*)&out[(size_t)gr * COUT + tc * 4] = o0;
            if constexpr (CT == 8) {
                float4 o1 = {acc[j][4] * dv, acc[j][5] * dv, acc[j][6] * dv, acc[j][7] * dv};
                *(float4*)&out[(size_t)gr * COUT + COUT / 2 + tc * 4] = o1;
            }
        }
    }
}

// 128-wide packed gather (layer 2): 32 lanes x float4 = one full row ->
// 2 edges per wave-instruction; 16 edges/iteration, masked. shfl_xor(32).
__global__ __launch_bounds__(256) void k_gather128p(const float* __restrict__ tab,
                                                    const int* __restrict__ rptr,
                                                    const int* __restrict__ col,
                                                    const float* __restrict__ dinv,
                                                    const float* __restrict__ b,
                                                    float* __restrict__ out, int n) {
    const int wave = threadIdx.x >> 6;
    const int lane = threadIdx.x & 63;
    const int g = lane >> 5;
    const int q = lane & 31;
    const int node = blockIdx.x * 4 + wave;
    if (node >= n) return;
    const int beg = rptr[node], end = rptr[node + 1];

    float4 acc = {0.f, 0.f, 0.f, 0.f};
    int j = beg;
    if (j < end) {
        int s[8]; bool val[8];
#pragma unroll
        for (int u = 0; u < 8; ++u) {
            int ei = j + 2 * u + g;
            val[u] = ei < end;
            s[u] = val[u] ? col[ei] : node;
        }
        j += 16;
        while (true) {
            float4 v[8];
#pragma unroll
            for (int u = 0; u < 8; ++u)
                v[u] = *(const float4*)&tab[(size_t)s[u] * 128 + q * 4];
            const bool more = j < end;
            int sn[8]; bool vn[8];
            if (more) {
#pragma unroll
                for (int u = 0; u < 8; ++u) {
                    int ei = j + 2 * u + g;
                    vn[u] = ei < end;
                    sn[u] = vn[u] ? col[ei] : node;
                }
            }
#pragma unroll
            for (int u = 0; u < 8; ++u) {
                if (val[u]) {
                    acc.x += v[u].x; acc.y += v[u].y;
                    acc.z += v[u].z; acc.w += v[u].w;
                }
            }
            if (!more) break;
#pragma unroll
            for (int u = 0; u < 8; ++u) { s[u] = sn[u]; val[u] = vn[u]; }
            j += 16;
        }
    }
    acc.x += __shfl_xor(acc.x, 32, 64); acc.y += __shfl_xor(acc.y, 32, 64);
    acc.z += __shfl_xor(acc.z, 32, 64); acc.w += __shfl_xor(acc.w, 32, 64);

    if (g == 0) {
        float4 self = *(const float4*)&tab[(size_t)node * 128 + q * 4];
        float dn = dinv[node];
        float4 bb = ((const float4*)b)[q];
        float4 o = {(acc.x + self.x) * dn + bb.x, (acc.y + self.y) * dn + bb.y,
                    (acc.z + self.z) * dn + bb.z, (acc.w + self.w) * dn + bb.w};
        *(float4*)&out[(size_t)node * 128 + q * 4] = o;
    }
}

// 64-wide packed gather, MODE 1 (layer 3): out = dn*relu((sum+self)*dn + b)
__global__ __launch_bounds__(256) void k_gather64p(const float* __restrict__ tab,
                                                   const int* __restrict__ rptr,
                                                   const int* __restrict__ col,
                                                   const float* __restrict__ dinv,
                                                   const float* __restrict__ b,
                                                   float* __restrict__ out, int n) {
    const int wave = threadIdx.x >> 6;
    const int lane = threadIdx.x & 63;
    const int g = lane >> 4;
    const int q = lane & 15;
    const int node = blockIdx.x * 4 + wave;
    if (node >= n) return;
    const int beg = rptr[node], end = rptr[node + 1];

    float4 acc = {0.f, 0.f, 0.f, 0.f};
    int j = beg;
    if (j < end) {
        int s[4]; bool val[4];
#pragma unroll
        for (int u = 0; u < 4; ++u) {
            int ei = j + 4 * u + g;
            val[u] = ei < end;
            s[u] = val[u] ? col[ei] : node;
        }
        j += 16;
        while (true) {
            float4 v[4];
#pragma unroll
            for (int u = 0; u < 4; ++u)
                v[u] = *(const float4*)&tab[(size_t)s[u] * 64 + q * 4];
            const bool more = j < end;
            int sn[4]; bool vn[4];
            if (more) {
#pragma unroll
                for (int u = 0; u < 4; ++u) {
                    int ei = j + 4 * u + g;
                    vn[u] = ei < end;
                    sn[u] = vn[u] ? col[ei] : node;
                }
            }
#pragma unroll
            for (int u = 0; u < 4; ++u) {
                if (val[u]) {
                    acc.x += v[u].x; acc.y += v[u].y;
                    acc.z += v[u].z; acc.w += v[u].w;
                }
            }
            if (!more) break;
#pragma unroll
            for (int u = 0; u < 4; ++u) { s[u] = sn[u]; val[u] = vn[u]; }
            j += 16;
        }
    }
    acc.x += __shfl_xor(acc.x, 16, 64); acc.y += __shfl_xor(acc.y, 16, 64);
    acc.z += __shfl_xor(acc.z, 16, 64); acc.w += __shfl_xor(acc.w, 16, 64);
    acc.x += __shfl_xor(acc.x, 32, 64); acc.y += __shfl_xor(acc.y, 32, 64);
    acc.z += __shfl_xor(acc.z, 32, 64); acc.w += __shfl_xor(acc.w, 32, 64);

    if (g == 0) {
        float4 self = *(const float4*)&tab[(size_t)node * 64 + q * 4];
        float dn = dinv[node];
        float4 bb = ((const float4*)b)[q];
        float4 o = {(acc.x + self.x) * dn, (acc.y + self.y) * dn,
                    (acc.z + self.z) * dn, (acc.w + self.w) * dn};
        o.x = fmaxf(o.x + bb.x, 0.f) * dn;
        o.y = fmaxf(o.y + bb.y, 0.f) * dn;
        o.z = fmaxf(o.z + bb.z, 0.f) * dn;
        o.w = fmaxf(o.w + bb.w, 0.f) * dn;
        *(float4*)&out[(size_t)node * 64 + q * 4] = o;
    }
}

// fused heads: per node, gather g3 = A-hat(tab) (packed 4 edges/instr),
// then mu/ls = g3 @ [Wmu|Wls] + bias, with g3 broadcast via shfl and
// interleaved Wpair staged in LDS. 32 nodes/block (8 per wave, serial).
__global__ __launch_bounds__(256) void k_gather_heads(const float* __restrict__ tab,
                                                      const int* __restrict__ rptr,
                                                      const int* __restrict__ col,
                                                      const float* __restrict__ dinv,
                                                      const float* __restrict__ bmu,
                                                      const float* __restrict__ bls,
                                                      const float2* __restrict__ Wpair,
                                                      float* __restrict__ mu,
                                                      float* __restrict__ ls, int n) {
    __shared__ float2 wp[64 * 64];   // 32 KB: wp[k*64+c] = {Wmu[k][c], Wls[k][c]}
    for (int f = threadIdx.x; f < 64 * 64 / 2; f += 256)
        ((float4*)wp)[f] = ((const float4*)Wpair)[f];
    __syncthreads();

    const int wave = threadIdx.x >> 6;
    const int lane = threadIdx.x & 63;
    const int g = lane >> 4;
    const int q = lane & 15;
    const float bmu_c = bmu[lane];
    const float bls_c = bls[lane];

    for (int i = 0; i < 8; ++i) {
        const int node = blockIdx.x * 32 + wave * 8 + i;
        if (node >= n) break;
        const int beg = rptr[node], end = rptr[node + 1];

        float4 acc = {0.f, 0.f, 0.f, 0.f};
        int j = beg;
        if (j < end) {
            int s[4]; bool val[4];
#pragma unroll
            for (int u = 0; u < 4; ++u) {
                int ei = j + 4 * u + g;
                val[u] = ei < end;
                s[u] = val[u] ? col[ei] : node;
            }
            j += 16;
            while (true) {
                float4 v[4];
#pragma unroll
                for (int u = 0; u < 4; ++u)
                    v[u] = *(const float4*)&tab[(size_t)s[u] * 64 + q * 4];
                const bool more = j < end;
                int sn[4]; bool vn[4];
                if (more) {
#pragma unroll
                    for (int u = 0; u < 4; ++u) {
                        int ei = j + 4 * u + g;
                        vn[u] = ei < end;
                        sn[u] = vn[u] ? col[ei] : node;
                    }
                }
#pragma unroll
                for (int u = 0; u < 4; ++u) {
                    if (val[u]) {
                        acc.x += v[u].x; acc.y += v[u].y;
                        acc.z += v[u].z; acc.w += v[u].w;
                    }
                }
                if (!more) break;
#pragma unroll
                for (int u = 0; u < 4; ++u) { s[u] = sn[u]; val[u] = vn[u]; }
                j += 16;
            }
        }
        acc.x += __shfl_xor(acc.x, 16, 64); acc.y += __shfl_xor(acc.y, 16, 64);
        acc.z += __shfl_xor(acc.z, 16, 64); acc.w += __shfl_xor(acc.w, 16, 64);
        acc.x += __shfl_xor(acc.x, 32, 64); acc.y += __shfl_xor(acc.y, 32, 64);
        acc.z += __shfl_xor(acc.z, 32, 64); acc.w += __shfl_xor(acc.w, 32, 64);

        // g3[4q..4q+3] on lanes 0..15 (g==0); others hold same sums (harmless)
        const float dn = dinv[node];
        float4 self = *(const float4*)&tab[(size_t)node * 64 + q * 4];
        float4 o = {(acc.x + self.x) * dn, (acc.y + self.y) * dn,
                    (acc.z + self.z) * dn, (acc.w + self.w) * dn};

        // mu/ls[c] = sum_k g3[k] * Wpair[k][c] ; broadcast g3 via shfl
        float am = 0.f, al = 0.f;
#pragma unroll
        for (int qq = 0; qq < 16; ++qq) {
            float r0 = __shfl(o.x, qq, 64);
            float r1 = __shfl(o.y, qq, 64);
            float r2 = __shfl(o.z, qq, 64);
            float r3 = __shfl(o.w, qq, 64);
            const int k0 = qq * 4;
            float2 w0 = wp[(k0 + 0) * 64 + lane];
            float2 w1 = wp[(k0 + 1) * 64 + lane];
            float2 w2 = wp[(k0 + 2) * 64 + lane];
            float2 w3 = wp[(k0 + 3) * 64 + lane];
            am = fmaf(r0, w0.x, am); al = fmaf(r0, w0.y, al);
            am = fmaf(r1, w1.x, am); al = fmaf(r1, w1.y, al);
            am = fmaf(r2, w2.x, am); al = fmaf(r2, w2.y, al);
            am = fmaf(r3, w3.x, am); al = fmaf(r3, w3.y, al);
        }
        mu[(size_t)node * 64 + lane] = am + bmu_c;
        ls[(size_t)node * 64 + lane] = al + bls_c;
    }
}

extern "C" void kernel_launch(void* const* d_in, const int* in_sizes, int n_in,
                              void* d_out, int out_size, void* d_ws, size_t ws_size,
                              hipStream_t stream) {
    const int*   x    = (const int*)d_in[0];
    const int*   ei   = (const int*)d_in[1];
    const float* embW = (const float*)d_in[2];
    const float* W1   = (const float*)d_in[3];
    const float* b1   = (const float*)d_in[4];
    const float* W2   = (const float*)d_in[5];
    const float* b2   = (const float*)d_in[6];
    const float* W3   = (const float*)d_in[7];
    const float* b3   = (const float*)d_in[8];
    const float* Wmu  = (const float*)d_in[9];
    const float* bmu  = (const float*)d_in[10];
    const float* Wls  = (const float*)d_in[11];
    const float* bls  = (const float*)d_in[12];

    const int n = in_sizes[0];
    const int e = in_sizes[1] / 2;
    const int V = in_sizes[2] / 128;
    const int* src = ei;
    const int* dst = ei + e;

    char* w = (char*)d_ws;
    auto alloc = [&](size_t bytes) {
        char* p = w;
        w += (bytes + 255) & ~(size_t)255;
        return p;
    };
    float* bufA = (float*)alloc((size_t)n * 128 * 4);
    float* bufB = (float*)alloc((size_t)n * 128 * 4);
    float* hW   = (float*)alloc((size_t)n * 128 * 4);
    int*   rptr = (int*)alloc((size_t)(n + 1) * 4);
    int*   col  = (int*)alloc((size_t)e * 4);
    int*   pck  = (int*)alloc((size_t)e * 4);
    float* dinv = (float*)alloc((size_t)n * 4);
    int2*  xd   = (int2*)alloc((size_t)n * 8);
    float2* Wpr = (float2*)alloc((size_t)64 * 64 * 8);
    float* Msm  = (float*)alloc((size_t)32 * 128 * 4);
    int*   boff = (int*)alloc((size_t)257 * 4);

    const int ntile = (e + 4095) / 4096;
    const int nbuck = (n + 255) / 256;
    int* hist_g = (int*)alloc((size_t)ntile * 256 * 4);
    int* tbase  = (int*)alloc((size_t)ntile * 256 * 4);

    const int nsm = (V + 1) / 2;

    // ---- atomic-free CSR build (reused by all layers) ----
    k_hist <<<ntile, 256, 0, stream>>>(dst, hist_g, e);
    k_scan2<<<1, 256, 0, stream>>>(hist_g, tbase, boff, ntile);
    k_binA3<<<ntile, 256, 0, stream>>>(src, dst, boff, tbase, pck, e);
    k_binB2<<<nbuck, 256, 0, stream>>>(pck, boff, x, rptr, dinv, xd, col, n);
    k_prepW<<<nsm + 16, 256, 0, stream>>>(embW, W1, Wmu, Wls, Msm, Wpr, V, nsm);

    const int gmm = (n + 127) / 128;
    const int ggt = (n + 3) / 4;
    float* mu = (float*)d_out;
    float* ls = (float*)d_out + (size_t)n * 64;

    // layer 1: 28-row LDS-table gather
    k_gather_l1<<<ggt, 256, 0, stream>>>(Msm, rptr, col, xd, b1, bufA, n, V);
    // layer 2: matmul (relu on load) + packed 128-wide gather
    k_matmul<128, 128, true><<<gmm, 256, 0, stream>>>(bufA, W2, dinv, hW, n);
    k_gather128p<<<ggt, 256, 0, stream>>>(hW, rptr, col, dinv, b2, bufB, n);
    // layer 3: matmul 128->64 + packed 64-wide gather, out = dinv*relu(conv3)
    k_matmul<128, 64, true><<<gmm, 256, 0, stream>>>(bufB, W3, dinv, hW, n);
    k_gather64p<<<ggt, 256, 0, stream>>>(hW, rptr, col, dinv, b3, bufA, n);
    // heads: fused gather + 64->128 matmul + bias, direct mu/ls write
    k_gather_heads<<<(n + 31) / 32, 256, 0, stream>>>(bufA, rptr, col, dinv,
                                                      bmu, bls, Wpr, mu, ls, n);
}

// Round 11
// 313.182 us; speedup vs baseline: 1.0984x; 1.0984x over previous
//
#include <hip/hip_runtime.h>
#include <hip/hip_bf16.h>
#include <cstddef>

// ---------------------------------------------------------------------------
// GCN variational encoder: N nodes, E edges, H=128 hidden, C=64 out.
// A(HW) = (AH)W lets each layer gather in the narrow domain.
// Gathers: per-VMEM-instruction packed; 128-wide gather sits at the random
// 64B-line L2-fill fabric ceiling (~186MB @ ~3.8TB/s) -- accepted floor.
// Heads fusion REVERTED (R10: -55% occupancy + serial node loop killed MLP).
// CSR build: atomic-free 3-phase (per-tile hist -> bucket+tile scan ->
// LDS-ranked scatter -> per-bucket sort emitting rptr/dinv/xd/col).
// ---------------------------------------------------------------------------

// ---- CSR pipeline (bucket = dst>>8; requires n <= 65536) ----

__global__ __launch_bounds__(256) void k_hist(const int* __restrict__ dst,
                                              int* __restrict__ hist_g, int e) {
    __shared__ int h[256];
    const int tid = threadIdx.x;
    h[tid] = 0;
    __syncthreads();
    const int e0 = blockIdx.x * 4096;
    const int e1 = min(e0 + 4096, e);
    for (int j = e0 + tid; j < e1; j += 256) atomicAdd(&h[dst[j] >> 8], 1);
    __syncthreads();
    hist_g[blockIdx.x * 256 + tid] = h[tid];
}

// single block: per-bucket scan over tiles -> tbase; bucket scan -> boff[257]
__global__ __launch_bounds__(256) void k_scan2(const int* __restrict__ hist_g,
                                               int* __restrict__ tbase,
                                               int* __restrict__ boff, int ntile) {
    const int b = threadIdx.x;
    int acc = 0;
    for (int t = 0; t < ntile; ++t) {
        int v = hist_g[t * 256 + b];
        tbase[t * 256 + b] = acc;
        acc += v;
    }
    __shared__ int wsum[4];
    const int lane = b & 63, wv = b >> 6;
    int v = acc;
#pragma unroll
    for (int d = 1; d < 64; d <<= 1) {
        int w = __shfl_up(v, d, 64);
        if (lane >= d) v += w;
    }
    if (lane == 63) wsum[wv] = v;
    __syncthreads();
    int woff = 0;
    for (int w = 0; w < wv; ++w) woff += wsum[w];
    int excl = woff + v - acc;
    boff[b] = excl;
    if (b == 255) boff[256] = excl + acc;
}

// single-pass scatter: packed (dlocal<<16 | src) at boff[b]+tbase[tile][b]+rank
__global__ __launch_bounds__(256) void k_binA3(const int* __restrict__ src,
                                               const int* __restrict__ dst,
                                               const int* __restrict__ boff,
                                               const int* __restrict__ tbase,
                                               int* __restrict__ packed, int e) {
    __shared__ int hist[256];
    __shared__ int base[256];
    const int tid = threadIdx.x;
    const int e0 = blockIdx.x * 4096;
    const int e1 = min(e0 + 4096, e);
    hist[tid] = 0;
    base[tid] = boff[tid] + tbase[blockIdx.x * 256 + tid];
    __syncthreads();
    for (int j = e0 + tid; j < e1; j += 256) {
        int d = dst[j];
        int b = d >> 8;
        int r = atomicAdd(&hist[b], 1);
        packed[base[b] + r] = ((d & 255) << 16) | src[j];
    }
}

// per bucket: node hist + in-block scan -> rptr/dinv/xd; LDS sort -> col
#define BCAP 6144
__global__ __launch_bounds__(256) void k_binB2(const int* __restrict__ packed,
                                               const int* __restrict__ boff,
                                               const int* __restrict__ x,
                                               int* __restrict__ rptr,
                                               float* __restrict__ dinv,
                                               int2* __restrict__ xd,
                                               int* __restrict__ col,
                                               int n) {
    __shared__ int hist[256];
    __shared__ int cur[256];
    __shared__ int wsum[4];
    __shared__ int buf[BCAP];
    const int tid = threadIdx.x;
    const int lane = tid & 63, wv = tid >> 6;
    const int node0 = blockIdx.x << 8;
    const int node1 = min(node0 + 256, n);
    const int ebeg = boff[blockIdx.x];
    const int eend = boff[blockIdx.x + 1];
    const int cnt = eend - ebeg;

    hist[tid] = 0;
    __syncthreads();
    for (int j = tid; j < cnt; j += 256) atomicAdd(&hist[packed[ebeg + j] >> 16], 1);
    __syncthreads();
    const int deg = hist[tid];
    int v = deg;
#pragma unroll
    for (int d = 1; d < 64; d <<= 1) {
        int w = __shfl_up(v, d, 64);
        if (lane >= d) v += w;
    }
    if (lane == 63) wsum[wv] = v;
    __syncthreads();
    int woff = 0;
    for (int w = 0; w < wv; ++w) woff += wsum[w];
    const int excl = woff + v - deg;
    cur[tid] = excl;
    const int node = node0 + tid;
    if (node < node1) {
        rptr[node] = ebeg + excl;
        float dv = 1.0f / sqrtf((float)(deg + 1));
        dinv[node] = dv;
        xd[node] = make_int2(x[node], __float_as_int(dv));
    }
    if (node1 == n && tid == 0) rptr[n] = eend;
    __syncthreads();

    if (cnt <= BCAP) {
        for (int j = tid; j < cnt; j += 256) {
            int p = packed[ebeg + j];
            int pos = atomicAdd(&cur[p >> 16], 1);
            buf[pos] = p & 0xffff;
        }
        __syncthreads();
        for (int j = tid; j < cnt; j += 256) col[ebeg + j] = buf[j];
    } else {
        for (int j = tid; j < cnt; j += 256) {
            int p = packed[ebeg + j];
            int pos = atomicAdd(&cur[p >> 16], 1);
            col[ebeg + pos] = p & 0xffff;
        }
    }
}

// fused weight prep: blocks [0,nsm): M = embW @ W1 (2 rows/block);
// blocks [nsm, nsm+32): Wcat[k*128+c] = c<64 ? Wmu[k][c] : Wls[k][c-64]
__global__ __launch_bounds__(256) void k_prepW(const float* __restrict__ embW,
                                               const float* __restrict__ W1,
                                               const float* __restrict__ Wmu,
                                               const float* __restrict__ Wls,
                                               float* __restrict__ M,
                                               float* __restrict__ Wcat,
                                               int V, int nsm) {
    if ((int)blockIdx.x < nsm) {
        const int r = blockIdx.x * 2 + (threadIdx.x >> 7);
        const int c = threadIdx.x & 127;
        if (r >= V) return;
        float a0 = 0.f, a1 = 0.f;
        const float* er = embW + (size_t)r * 128;
#pragma unroll 4
        for (int k = 0; k < 128; k += 2) {
            a0 = fmaf(er[k], W1[(size_t)k * 128 + c], a0);
            a1 = fmaf(er[k + 1], W1[(size_t)(k + 1) * 128 + c], a1);
        }
        M[(size_t)r * 128 + c] = a0 + a1;
    } else {
        int i = (blockIdx.x - nsm) * 256 + threadIdx.x;
        if (i < 64 * 128) {
            int k = i >> 7, c = i & 127;
            Wcat[i] = (c < 64) ? Wmu[k * 64 + c] : Wls[k * 64 + (c - 64)];
        }
    }
}

// layer-1 gather: M table (V<=32 rows x 128) in LDS; per edge read packed
// xd[s]={x,dinv} (8B, L2-resident) and accumulate dinv * M[x].
__global__ __launch_bounds__(256) void k_gather_l1(const float* __restrict__ M,
                                                   const int* __restrict__ rptr,
                                                   const int* __restrict__ col,
                                                   const int2* __restrict__ xd,
                                                   const float* __restrict__ b,
                                                   float* __restrict__ out,
                                                   int n, int V) {
    __shared__ float sh[32 * 128];
    for (int f = threadIdx.x; f < V * 32; f += 256)
        ((float4*)sh)[f] = ((const float4*)M)[f];
    __syncthreads();

    const int wave = threadIdx.x >> 6;
    const int lane = threadIdx.x & 63;
    const int node = blockIdx.x * 4 + wave;
    if (node >= n) return;
    const int beg = rptr[node], end = rptr[node + 1];
    int j = beg;

    float ax0 = 0.f, ay0 = 0.f, ax1 = 0.f, ay1 = 0.f;
    const int lo = 2 * lane;
    if (end - beg >= 8) {
        int s[8];
#pragma unroll
        for (int u = 0; u < 8; ++u) s[u] = col[j + u];
        j += 8;
        while (true) {
            int2 p[8];
#pragma unroll
            for (int u = 0; u < 8; ++u) p[u] = xd[s[u]];
            const bool more = (j + 8 <= end);
            int sn[8];
            if (more) {
#pragma unroll
                for (int u = 0; u < 8; ++u) sn[u] = col[j + u];
            }
#pragma unroll
            for (int u = 0; u < 8; ++u) {
                float dv = __int_as_float(p[u].y);
                float2 v = *(const float2*)&sh[p[u].x * 128 + lo];
                if (u & 1) { ax1 = fmaf(dv, v.x, ax1); ay1 = fmaf(dv, v.y, ay1); }
                else       { ax0 = fmaf(dv, v.x, ax0); ay0 = fmaf(dv, v.y, ay0); }
            }
            if (!more) break;
#pragma unroll
            for (int u = 0; u < 8; ++u) s[u] = sn[u];
            j += 8;
        }
    }
    for (; j < end; ++j) {
        int2 p = xd[col[j]];
        float dv = __int_as_float(p.y);
        float2 v = *(const float2*)&sh[p.x * 128 + lo];
        ax0 = fmaf(dv, v.x, ax0); ay0 = fmaf(dv, v.y, ay0);
    }
    int2 pn = xd[node];
    float dn = __int_as_float(pn.y);
    float2 sv = *(const float2*)&sh[pn.x * 128 + lo];
    float2 bb = ((const float2*)b)[lane];
    float ox = (ax0 + ax1 + dn * sv.x) * dn + bb.x;
    float oy = (ay0 + ay1 + dn * sv.y) * dn + bb.y;
    ((float2*)out)[(size_t)node * 64 + lane] = {ox, oy};
}

// out[r][c] = dinv[r] * sum_k act(in[r][k]) * W[k][c]
// BM=128, KC=32; 256 threads; per-thread 8 rows x CT*4 cols register tile.
template <int K, int COUT, bool RELU>
__global__ __launch_bounds__(256) void k_matmul(const float* __restrict__ in,
                                                const float* __restrict__ W,
                                                const float* __restrict__ dinv,
                                                float* __restrict__ out, int n) {
    constexpr int BM = 128, KC = 32, LDI = KC + 4;
    constexpr int CT = COUT / 16;
    __shared__ float sIn[BM * LDI];
    __shared__ float sW[KC * COUT];

    const int tid = threadIdx.x;
    const int row0 = blockIdx.x * BM;
    const int tc = tid & 15;
    const int tr = tid >> 4;

    float acc[8][CT];
#pragma unroll
    for (int j = 0; j < 8; ++j)
#pragma unroll
        for (int c = 0; c < CT; ++c) acc[j][c] = 0.f;

    const int sr = tid >> 3;
    const int sk = (tid & 7) * 4;

    for (int kc = 0; kc < K; kc += KC) {
#pragma unroll
        for (int p = 0; p < 4; ++p) {
            int rr = p * 32 + sr;
            int gr = row0 + rr;
            float4 v = {0.f, 0.f, 0.f, 0.f};
            if (gr < n) v = *(const float4*)&in[(size_t)gr * K + kc + sk];
            if (RELU) {
                v.x = fmaxf(v.x, 0.f); v.y = fmaxf(v.y, 0.f);
                v.z = fmaxf(v.z, 0.f); v.w = fmaxf(v.w, 0.f);
            }
            *(float4*)&sIn[rr * LDI + sk] = v;
        }
        for (int f4 = tid; f4 < KC * COUT / 4; f4 += 256)
            *(float4*)&sW[f4 * 4] = *(const float4*)&W[(size_t)kc * COUT + f4 * 4];
        __syncthreads();

        for (int kk = 0; kk < KC; kk += 4) {
            float4 a[8];
#pragma unroll
            for (int j = 0; j < 8; ++j)
                a[j] = *(const float4*)&sIn[(tr * 8 + j) * LDI + kk];
#pragma unroll
            for (int t = 0; t < 4; ++t) {
                float4 w0 = *(const float4*)&sW[(kk + t) * COUT + tc * 4];
                float4 w1;
                if constexpr (CT == 8)
                    w1 = *(const float4*)&sW[(kk + t) * COUT + COUT / 2 + tc * 4];
#pragma unroll
                for (int j = 0; j < 8; ++j) {
                    float av = (t == 0) ? a[j].x : (t == 1) ? a[j].y
                             : (t == 2) ? a[j].z : a[j].w;
                    acc[j][0] = fmaf(av, w0.x, acc[j][0]);
                    acc[j][1] = fmaf(av, w0.y, acc[j][1]);
                    acc[j][2] = fmaf(av, w0.z, acc[j][2]);
                    acc[j][3] = fmaf(av, w0.w, acc[j][3]);
                    if constexpr (CT == 8) {
                        acc[j][4] = fmaf(av, w1.x, acc[j][4]);
                        acc[j][5] = fmaf(av, w1.y, acc[j][5]);
                        acc[j][6] = fmaf(av, w1.z, acc[j][6]);
                        acc[j][7] = fmaf(av, w1.w, acc[j][7]);
                    }
                }
            }
        }
        __syncthreads();
    }

#pragma unroll
    for (int j = 0; j < 8; ++j) {
        int gr = row0 + tr * 8 + j;
        if (gr < n) {
            float dv = dinv[gr];
            float4 o0 = {acc[j][0] * dv, acc[j][1] * dv, acc[j][2] * dv, acc[j][3] * dv};
            *(float4*)&out[(size_t)gr * COUT + tc * 4] = o0;
            if constexpr (CT == 8) {
                float4 o1 = {acc[j][4] * dv, acc[j][5] * dv, acc[j][6] * dv, acc[j][7] * dv};
                *(float4*)&out[(size_t)gr * COUT + COUT / 2 + tc * 4] = o1;
            }
        }
    }
}

// heads matmul: out = g3 (N x 64) @ Wcat (64 x 128) + [bmu|bls] -> mu, ls
__global__ __launch_bounds__(256) void k_mm_heads(const float* __restrict__ in,
                                                  const float* __restrict__ W,
                                                  const float* __restrict__ bmu,
                                                  const float* __restrict__ bls,
                                                  float* __restrict__ mu,
                                                  float* __restrict__ ls, int n) {
    constexpr int BM = 128, KC = 32, LDI = KC + 4, K = 64, COUT = 128;
    __shared__ float sIn[BM * LDI];
    __shared__ float sW[KC * COUT];

    const int tid = threadIdx.x;
    const int row0 = blockIdx.x * BM;
    const int tc = tid & 15;
    const int tr = tid >> 4;

    float acc[8][8];
#pragma unroll
    for (int j = 0; j < 8; ++j)
#pragma unroll
        for (int c = 0; c < 8; ++c) acc[j][c] = 0.f;

    const int sr = tid >> 3;
    const int sk = (tid & 7) * 4;

    for (int kc = 0; kc < K; kc += KC) {
#pragma unroll
        for (int p = 0; p < 4; ++p) {
            int rr = p * 32 + sr;
            int gr = row0 + rr;
            float4 v = {0.f, 0.f, 0.f, 0.f};
            if (gr < n) v = *(const float4*)&in[(size_t)gr * K + kc + sk];
            *(float4*)&sIn[rr * LDI + sk] = v;
        }
        for (int f4 = tid; f4 < KC * COUT / 4; f4 += 256)
            *(float4*)&sW[f4 * 4] = *(const float4*)&W[(size_t)kc * COUT + f4 * 4];
        __syncthreads();

        for (int kk = 0; kk < KC; kk += 4) {
            float4 a[8];
#pragma unroll
            for (int j = 0; j < 8; ++j)
                a[j] = *(const float4*)&sIn[(tr * 8 + j) * LDI + kk];
#pragma unroll
            for (int t = 0; t < 4; ++t) {
                float4 w0 = *(const float4*)&sW[(kk + t) * COUT + tc * 4];
                float4 w1 = *(const float4*)&sW[(kk + t) * COUT + 64 + tc * 4];
#pragma unroll
                for (int j = 0; j < 8; ++j) {
                    float av = (t == 0) ? a[j].x : (t == 1) ? a[j].y
                             : (t == 2) ? a[j].z : a[j].w;
                    acc[j][0] = fmaf(av, w0.x, acc[j][0]);
                    acc[j][1] = fmaf(av, w0.y, acc[j][1]);
                    acc[j][2] = fmaf(av, w0.z, acc[j][2]);
                    acc[j][3] = fmaf(av, w0.w, acc[j][3]);
                    acc[j][4] = fmaf(av, w1.x, acc[j][4]);
                    acc[j][5] = fmaf(av, w1.y, acc[j][5]);
                    acc[j][6] = fmaf(av, w1.z, acc[j][6]);
                    acc[j][7] = fmaf(av, w1.w, acc[j][7]);
                }
            }
        }
        __syncthreads();
    }

    float4 bm = ((const float4*)bmu)[tc];
    float4 bl = ((const float4*)bls)[tc];
#pragma unroll
    for (int j = 0; j < 8; ++j) {
        int gr = row0 + tr * 8 + j;
        if (gr < n) {
            float4 o0 = {acc[j][0] + bm.x, acc[j][1] + bm.y, acc[j][2] + bm.z, acc[j][3] + bm.w};
            float4 o1 = {acc[j][4] + bl.x, acc[j][5] + bl.y, acc[j][6] + bl.z, acc[j][7] + bl.w};
            *(float4*)&mu[(size_t)gr * 64 + tc * 4] = o0;
            *(float4*)&ls[(size_t)gr * 64 + tc * 4] = o1;
        }
    }
}

// 128-wide packed gather (layer 2): 32 lanes x float4 = one full row ->
// 2 edges per wave-instruction; 16 edges/iteration, masked. shfl_xor(32).
__global__ __launch_bounds__(256) void k_gather128p(const float* __restrict__ tab,
                                                    const int* __restrict__ rptr,
                                                    const int* __restrict__ col,
                                                    const float* __restrict__ dinv,
                                                    const float* __restrict__ b,
                                                    float* __restrict__ out, int n) {
    const int wave = threadIdx.x >> 6;
    const int lane = threadIdx.x & 63;
    const int g = lane >> 5;
    const int q = lane & 31;
    const int node = blockIdx.x * 4 + wave;
    if (node >= n) return;
    const int beg = rptr[node], end = rptr[node + 1];

    float4 acc = {0.f, 0.f, 0.f, 0.f};
    int j = beg;
    if (j < end) {
        int s[8]; bool val[8];
#pragma unroll
        for (int u = 0; u < 8; ++u) {
            int ei = j + 2 * u + g;
            val[u] = ei < end;
            s[u] = val[u] ? col[ei] : node;
        }
        j += 16;
        while (true) {
            float4 v[8];
#pragma unroll
            for (int u = 0; u < 8; ++u)
                v[u] = *(const float4*)&tab[(size_t)s[u] * 128 + q * 4];
            const bool more = j < end;
            int sn[8]; bool vn[8];
            if (more) {
#pragma unroll
                for (int u = 0; u < 8; ++u) {
                    int ei = j + 2 * u + g;
                    vn[u] = ei < end;
                    sn[u] = vn[u] ? col[ei] : node;
                }
            }
#pragma unroll
            for (int u = 0; u < 8; ++u) {
                if (val[u]) {
                    acc.x += v[u].x; acc.y += v[u].y;
                    acc.z += v[u].z; acc.w += v[u].w;
                }
            }
            if (!more) break;
#pragma unroll
            for (int u = 0; u < 8; ++u) { s[u] = sn[u]; val[u] = vn[u]; }
            j += 16;
        }
    }
    acc.x += __shfl_xor(acc.x, 32, 64); acc.y += __shfl_xor(acc.y, 32, 64);
    acc.z += __shfl_xor(acc.z, 32, 64); acc.w += __shfl_xor(acc.w, 32, 64);

    if (g == 0) {
        float4 self = *(const float4*)&tab[(size_t)node * 128 + q * 4];
        float dn = dinv[node];
        float4 bb = ((const float4*)b)[q];
        float4 o = {(acc.x + self.x) * dn + bb.x, (acc.y + self.y) * dn + bb.y,
                    (acc.z + self.z) * dn + bb.z, (acc.w + self.w) * dn + bb.w};
        *(float4*)&out[(size_t)node * 128 + q * 4] = o;
    }
}

// 64-wide packed gather: 16 lanes x float4 = one full row -> 4 edges/instr.
// MODE 1: out = dn*relu(o + b)  (layer 3);  MODE 2: out = o  (head pre-gather)
template <int MODE>
__global__ __launch_bounds__(256) void k_gather64p(const float* __restrict__ tab,
                                                   const int* __restrict__ rptr,
                                                   const int* __restrict__ col,
                                                   const float* __restrict__ dinv,
                                                   const float* __restrict__ b,
                                                   float* __restrict__ out, int n) {
    const int wave = threadIdx.x >> 6;
    const int lane = threadIdx.x & 63;
    const int g = lane >> 4;
    const int q = lane & 15;
    const int node = blockIdx.x * 4 + wave;
    if (node >= n) return;
    const int beg = rptr[node], end = rptr[node + 1];

    float4 acc = {0.f, 0.f, 0.f, 0.f};
    int j = beg;
    if (j < end) {
        int s[4]; bool val[4];
#pragma unroll
        for (int u = 0; u < 4; ++u) {
            int ei = j + 4 * u + g;
            val[u] = ei < end;
            s[u] = val[u] ? col[ei] : node;
        }
        j += 16;
        while (true) {
            float4 v[4];
#pragma unroll
            for (int u = 0; u < 4; ++u)
                v[u] = *(const float4*)&tab[(size_t)s[u] * 64 + q * 4];
            const bool more = j < end;
            int sn[4]; bool vn[4];
            if (more) {
#pragma unroll
                for (int u = 0; u < 4; ++u) {
                    int ei = j + 4 * u + g;
                    vn[u] = ei < end;
                    sn[u] = vn[u] ? col[ei] : node;
                }
            }
#pragma unroll
            for (int u = 0; u < 4; ++u) {
                if (val[u]) {
                    acc.x += v[u].x; acc.y += v[u].y;
                    acc.z += v[u].z; acc.w += v[u].w;
                }
            }
            if (!more) break;
#pragma unroll
            for (int u = 0; u < 4; ++u) { s[u] = sn[u]; val[u] = vn[u]; }
            j += 16;
        }
    }
    acc.x += __shfl_xor(acc.x, 16, 64); acc.y += __shfl_xor(acc.y, 16, 64);
    acc.z += __shfl_xor(acc.z, 16, 64); acc.w += __shfl_xor(acc.w, 16, 64);
    acc.x += __shfl_xor(acc.x, 32, 64); acc.y += __shfl_xor(acc.y, 32, 64);
    acc.z += __shfl_xor(acc.z, 32, 64); acc.w += __shfl_xor(acc.w, 32, 64);

    if (g == 0) {
        float4 self = *(const float4*)&tab[(size_t)node * 64 + q * 4];
        float dn = dinv[node];
        float4 o = {(acc.x + self.x) * dn, (acc.y + self.y) * dn,
                    (acc.z + self.z) * dn, (acc.w + self.w) * dn};
        if constexpr (MODE == 1) {
            float4 bb = ((const float4*)b)[q];
            o.x = fmaxf(o.x + bb.x, 0.f) * dn;
            o.y = fmaxf(o.y + bb.y, 0.f) * dn;
            o.z = fmaxf(o.z + bb.z, 0.f) * dn;
            o.w = fmaxf(o.w + bb.w, 0.f) * dn;
        }
        *(float4*)&out[(size_t)node * 64 + q * 4] = o;
    }
}

extern "C" void kernel_launch(void* const* d_in, const int* in_sizes, int n_in,
                              void* d_out, int out_size, void* d_ws, size_t ws_size,
                              hipStream_t stream) {
    const int*   x    = (const int*)d_in[0];
    const int*   ei   = (const int*)d_in[1];
    const float* embW = (const float*)d_in[2];
    const float* W1   = (const float*)d_in[3];
    const float* b1   = (const float*)d_in[4];
    const float* W2   = (const float*)d_in[5];
    const float* b2   = (const float*)d_in[6];
    const float* W3   = (const float*)d_in[7];
    const float* b3   = (const float*)d_in[8];
    const float* Wmu  = (const float*)d_in[9];
    const float* bmu  = (const float*)d_in[10];
    const float* Wls  = (const float*)d_in[11];
    const float* bls  = (const float*)d_in[12];

    const int n = in_sizes[0];
    const int e = in_sizes[1] / 2;
    const int V = in_sizes[2] / 128;
    const int* src = ei;
    const int* dst = ei + e;

    char* w = (char*)d_ws;
    auto alloc = [&](size_t bytes) {
        char* p = w;
        w += (bytes + 255) & ~(size_t)255;
        return p;
    };
    float* bufA = (float*)alloc((size_t)n * 128 * 4);
    float* bufB = (float*)alloc((size_t)n * 128 * 4);
    float* hW   = (float*)alloc((size_t)n * 128 * 4);
    int*   rptr = (int*)alloc((size_t)(n + 1) * 4);
    int*   col  = (int*)alloc((size_t)e * 4);
    int*   pck  = (int*)alloc((size_t)e * 4);
    float* dinv = (float*)alloc((size_t)n * 4);
    int2*  xd   = (int2*)alloc((size_t)n * 8);
    float* Wcat = (float*)alloc((size_t)64 * 128 * 4);
    float* Msm  = (float*)alloc((size_t)32 * 128 * 4);
    int*   boff = (int*)alloc((size_t)257 * 4);

    const int ntile = (e + 4095) / 4096;
    const int nbuck = (n + 255) / 256;
    int* hist_g = (int*)alloc((size_t)ntile * 256 * 4);
    int* tbase  = (int*)alloc((size_t)ntile * 256 * 4);

    const int nsm = (V + 1) / 2;

    // ---- atomic-free CSR build (reused by all layers) ----
    k_hist <<<ntile, 256, 0, stream>>>(dst, hist_g, e);
    k_scan2<<<1, 256, 0, stream>>>(hist_g, tbase, boff, ntile);
    k_binA3<<<ntile, 256, 0, stream>>>(src, dst, boff, tbase, pck, e);
    k_binB2<<<nbuck, 256, 0, stream>>>(pck, boff, x, rptr, dinv, xd, col, n);
    k_prepW<<<nsm + 32, 256, 0, stream>>>(embW, W1, Wmu, Wls, Msm, Wcat, V, nsm);

    const int gmm = (n + 127) / 128;
    const int ggt = (n + 3) / 4;
    float* mu = (float*)d_out;
    float* ls = (float*)d_out + (size_t)n * 64;

    // layer 1: 28-row LDS-table gather
    k_gather_l1<<<ggt, 256, 0, stream>>>(Msm, rptr, col, xd, b1, bufA, n, V);
    // layer 2: matmul (relu on load) + packed 128-wide gather
    k_matmul<128, 128, true><<<gmm, 256, 0, stream>>>(bufA, W2, dinv, hW, n);
    k_gather128p<<<ggt, 256, 0, stream>>>(hW, rptr, col, dinv, b2, bufB, n);
    // layer 3: matmul 128->64 + packed 64-wide gather, out = dinv*relu(conv3)
    k_matmul<128, 64, true><<<gmm, 256, 0, stream>>>(bufB, W3, dinv, hW, n);
    k_gather64p<1><<<ggt, 256, 0, stream>>>(hW, rptr, col, dinv, b3, bufA, n);
    // heads: g3 = A*(dinv*relu(conv3)) packed gather, then 64->128 matmul
    k_gather64p<2><<<ggt, 256, 0, stream>>>(bufA, rptr, col, dinv, bmu, bufB, n);
    k_mm_heads<<<gmm, 256, 0, stream>>>(bufB, Wcat, bmu, bls, mu, ls, n);
}

// Round 12
// 270.930 us; speedup vs baseline: 1.2698x; 1.1560x over previous
//
#include <hip/hip_runtime.h>
#include <hip/hip_bf16.h>
#include <cstddef>

// ---------------------------------------------------------------------------
// GCN variational encoder: N nodes, E edges, H=128 hidden, C=64 out.
// A(HW) = (AH)W lets each layer gather in the narrow domain.
// Gathers: per-VMEM-instruction packed; 128-wide gather sits at the random
// 64B-line L2-fill fabric ceiling (~186MB @ ~3.8TB/s) -- accepted floor.
// CSR build: atomic-free 3-phase; tile-scan parallelized (R11's 1-block
// serial k_scan2 was a 196-deep latency chain, ~25us).
// ---------------------------------------------------------------------------

// ---- CSR pipeline (bucket = dst>>8; requires n <= 65536) ----

__global__ __launch_bounds__(256) void k_hist(const int* __restrict__ dst,
                                              int* __restrict__ hist_g, int e) {
    __shared__ int h[256];
    const int tid = threadIdx.x;
    h[tid] = 0;
    __syncthreads();
    const int e0 = blockIdx.x * 4096;
    const int e1 = min(e0 + 4096, e);
    for (int j = e0 + tid; j < e1; j += 256) atomicAdd(&h[dst[j] >> 8], 1);
    __syncthreads();
    hist_g[blockIdx.x * 256 + tid] = h[tid];
}

// one block per bucket: parallel scan over tiles -> tbase; total -> bsum
__global__ __launch_bounds__(256) void k_scanT(const int* __restrict__ hist_g,
                                               int* __restrict__ tbase,
                                               int* __restrict__ bsum, int ntile) {
    const int b = blockIdx.x;
    const int t = threadIdx.x;
    const int lane = t & 63, wv = t >> 6;
    __shared__ int wsum[4];
    int carry = 0;
    for (int c = 0; c < ntile; c += 256) {
        int tt = c + t;
        int v0 = (tt < ntile) ? hist_g[tt * 256 + b] : 0;
        int v = v0;
#pragma unroll
        for (int d = 1; d < 64; d <<= 1) {
            int w = __shfl_up(v, d, 64);
            if (lane >= d) v += w;
        }
        if (lane == 63) wsum[wv] = v;
        __syncthreads();
        int woff = 0;
        for (int w = 0; w < wv; ++w) woff += wsum[w];
        int tot = wsum[0] + wsum[1] + wsum[2] + wsum[3];
        if (tt < ntile) tbase[tt * 256 + b] = carry + woff + v - v0;
        carry += tot;
        __syncthreads();
    }
    if (t == 0) bsum[b] = carry;
}

// single block: exclusive scan bsum[256] -> boff[257]
__global__ __launch_bounds__(256) void k_bscan2(const int* __restrict__ bsum,
                                                int* __restrict__ boff) {
    __shared__ int wsum[4];
    const int t = threadIdx.x;
    const int lane = t & 63, wv = t >> 6;
    int v0 = bsum[t];
    int v = v0;
#pragma unroll
    for (int d = 1; d < 64; d <<= 1) {
        int w = __shfl_up(v, d, 64);
        if (lane >= d) v += w;
    }
    if (lane == 63) wsum[wv] = v;
    __syncthreads();
    int woff = 0;
    for (int w = 0; w < wv; ++w) woff += wsum[w];
    int excl = woff + v - v0;
    boff[t] = excl;
    if (t == 255) boff[256] = excl + v0;
}

// single-pass scatter: packed (dlocal<<16 | src) at boff[b]+tbase[tile][b]+rank
__global__ __launch_bounds__(256) void k_binA3(const int* __restrict__ src,
                                               const int* __restrict__ dst,
                                               const int* __restrict__ boff,
                                               const int* __restrict__ tbase,
                                               int* __restrict__ packed, int e) {
    __shared__ int hist[256];
    __shared__ int base[256];
    const int tid = threadIdx.x;
    const int e0 = blockIdx.x * 4096;
    const int e1 = min(e0 + 4096, e);
    hist[tid] = 0;
    base[tid] = boff[tid] + tbase[blockIdx.x * 256 + tid];
    __syncthreads();
    for (int j = e0 + tid; j < e1; j += 256) {
        int d = dst[j];
        int b = d >> 8;
        int r = atomicAdd(&hist[b], 1);
        packed[base[b] + r] = ((d & 255) << 16) | src[j];
    }
}

// per bucket: node hist + in-block scan -> rptr/dinv/xd; LDS sort -> col
#define BCAP 6144
__global__ __launch_bounds__(256) void k_binB2(const int* __restrict__ packed,
                                               const int* __restrict__ boff,
                                               const int* __restrict__ x,
                                               int* __restrict__ rptr,
                                               float* __restrict__ dinv,
                                               int2* __restrict__ xd,
                                               int* __restrict__ col,
                                               int n) {
    __shared__ int hist[256];
    __shared__ int cur[256];
    __shared__ int wsum[4];
    __shared__ int buf[BCAP];
    const int tid = threadIdx.x;
    const int lane = tid & 63, wv = tid >> 6;
    const int node0 = blockIdx.x << 8;
    const int node1 = min(node0 + 256, n);
    const int ebeg = boff[blockIdx.x];
    const int eend = boff[blockIdx.x + 1];
    const int cnt = eend - ebeg;

    hist[tid] = 0;
    __syncthreads();
    for (int j = tid; j < cnt; j += 256) atomicAdd(&hist[packed[ebeg + j] >> 16], 1);
    __syncthreads();
    const int deg = hist[tid];
    int v = deg;
#pragma unroll
    for (int d = 1; d < 64; d <<= 1) {
        int w = __shfl_up(v, d, 64);
        if (lane >= d) v += w;
    }
    if (lane == 63) wsum[wv] = v;
    __syncthreads();
    int woff = 0;
    for (int w = 0; w < wv; ++w) woff += wsum[w];
    const int excl = woff + v - deg;
    cur[tid] = excl;
    const int node = node0 + tid;
    if (node < node1) {
        rptr[node] = ebeg + excl;
        float dv = 1.0f / sqrtf((float)(deg + 1));
        dinv[node] = dv;
        xd[node] = make_int2(x[node], __float_as_int(dv));
    }
    if (node1 == n && tid == 0) rptr[n] = eend;
    __syncthreads();

    if (cnt <= BCAP) {
        for (int j = tid; j < cnt; j += 256) {
            int p = packed[ebeg + j];
            int pos = atomicAdd(&cur[p >> 16], 1);
            buf[pos] = p & 0xffff;
        }
        __syncthreads();
        for (int j = tid; j < cnt; j += 256) col[ebeg + j] = buf[j];
    } else {
        for (int j = tid; j < cnt; j += 256) {
            int p = packed[ebeg + j];
            int pos = atomicAdd(&cur[p >> 16], 1);
            col[ebeg + pos] = p & 0xffff;
        }
    }
}

// fused weight prep: blocks [0,nsm): M = embW @ W1 (2 rows/block);
// blocks [nsm, nsm+32): Wcat[k*128+c] = c<64 ? Wmu[k][c] : Wls[k][c-64]
__global__ __launch_bounds__(256) void k_prepW(const float* __restrict__ embW,
                                               const float* __restrict__ W1,
                                               const float* __restrict__ Wmu,
                                               const float* __restrict__ Wls,
                                               float* __restrict__ M,
                                               float* __restrict__ Wcat,
                                               int V, int nsm) {
    if ((int)blockIdx.x < nsm) {
        const int r = blockIdx.x * 2 + (threadIdx.x >> 7);
        const int c = threadIdx.x & 127;
        if (r >= V) return;
        float a0 = 0.f, a1 = 0.f;
        const float* er = embW + (size_t)r * 128;
#pragma unroll 4
        for (int k = 0; k < 128; k += 2) {
            a0 = fmaf(er[k], W1[(size_t)k * 128 + c], a0);
            a1 = fmaf(er[k + 1], W1[(size_t)(k + 1) * 128 + c], a1);
        }
        M[(size_t)r * 128 + c] = a0 + a1;
    } else {
        int i = (blockIdx.x - nsm) * 256 + threadIdx.x;
        if (i < 64 * 128) {
            int k = i >> 7, c = i & 127;
            Wcat[i] = (c < 64) ? Wmu[k * 64 + c] : Wls[k * 64 + (c - 64)];
        }
    }
}

// layer-1 gather: M table (V<=32 rows x 128) in LDS; per edge read packed
// xd[s]={x,dinv} (8B, L2-resident) and accumulate dinv * M[x].
__global__ __launch_bounds__(256) void k_gather_l1(const float* __restrict__ M,
                                                   const int* __restrict__ rptr,
                                                   const int* __restrict__ col,
                                                   const int2* __restrict__ xd,
                                                   const float* __restrict__ b,
                                                   float* __restrict__ out,
                                                   int n, int V) {
    __shared__ float sh[32 * 128];
    for (int f = threadIdx.x; f < V * 32; f += 256)
        ((float4*)sh)[f] = ((const float4*)M)[f];
    __syncthreads();

    const int wave = threadIdx.x >> 6;
    const int lane = threadIdx.x & 63;
    const int node = blockIdx.x * 4 + wave;
    if (node >= n) return;
    const int beg = rptr[node], end = rptr[node + 1];
    int j = beg;

    float ax0 = 0.f, ay0 = 0.f, ax1 = 0.f, ay1 = 0.f;
    const int lo = 2 * lane;
    if (end - beg >= 8) {
        int s[8];
#pragma unroll
        for (int u = 0; u < 8; ++u) s[u] = col[j + u];
        j += 8;
        while (true) {
            int2 p[8];
#pragma unroll
            for (int u = 0; u < 8; ++u) p[u] = xd[s[u]];
            const bool more = (j + 8 <= end);
            int sn[8];
            if (more) {
#pragma unroll
                for (int u = 0; u < 8; ++u) sn[u] = col[j + u];
            }
#pragma unroll
            for (int u = 0; u < 8; ++u) {
                float dv = __int_as_float(p[u].y);
                float2 v = *(const float2*)&sh[p[u].x * 128 + lo];
                if (u & 1) { ax1 = fmaf(dv, v.x, ax1); ay1 = fmaf(dv, v.y, ay1); }
                else       { ax0 = fmaf(dv, v.x, ax0); ay0 = fmaf(dv, v.y, ay0); }
            }
            if (!more) break;
#pragma unroll
            for (int u = 0; u < 8; ++u) s[u] = sn[u];
            j += 8;
        }
    }
    for (; j < end; ++j) {
        int2 p = xd[col[j]];
        float dv = __int_as_float(p.y);
        float2 v = *(const float2*)&sh[p.x * 128 + lo];
        ax0 = fmaf(dv, v.x, ax0); ay0 = fmaf(dv, v.y, ay0);
    }
    int2 pn = xd[node];
    float dn = __int_as_float(pn.y);
    float2 sv = *(const float2*)&sh[pn.x * 128 + lo];
    float2 bb = ((const float2*)b)[lane];
    float ox = (ax0 + ax1 + dn * sv.x) * dn + bb.x;
    float oy = (ay0 + ay1 + dn * sv.y) * dn + bb.y;
    ((float2*)out)[(size_t)node * 64 + lane] = {ox, oy};
}

// out[r][c] = dinv[r] * sum_k act(in[r][k]) * W[k][c]
// BM=128, KC=32; 256 threads; per-thread 8 rows x CT*4 cols register tile.
template <int K, int COUT, bool RELU>
__global__ __launch_bounds__(256) void k_matmul(const float* __restrict__ in,
                                                const float* __restrict__ W,
                                                const float* __restrict__ dinv,
                                                float* __restrict__ out, int n) {
    constexpr int BM = 128, KC = 32, LDI = KC + 4;
    constexpr int CT = COUT / 16;
    __shared__ float sIn[BM * LDI];
    __shared__ float sW[KC * COUT];

    const int tid = threadIdx.x;
    const int row0 = blockIdx.x * BM;
    const int tc = tid & 15;
    const int tr = tid >> 4;

    float acc[8][CT];
#pragma unroll
    for (int j = 0; j < 8; ++j)
#pragma unroll
        for (int c = 0; c < CT; ++c) acc[j][c] = 0.f;

    const int sr = tid >> 3;
    const int sk = (tid & 7) * 4;

    for (int kc = 0; kc < K; kc += KC) {
#pragma unroll
        for (int p = 0; p < 4; ++p) {
            int rr = p * 32 + sr;
            int gr = row0 + rr;
            float4 v = {0.f, 0.f, 0.f, 0.f};
            if (gr < n) v = *(const float4*)&in[(size_t)gr * K + kc + sk];
            if (RELU) {
                v.x = fmaxf(v.x, 0.f); v.y = fmaxf(v.y, 0.f);
                v.z = fmaxf(v.z, 0.f); v.w = fmaxf(v.w, 0.f);
            }
            *(float4*)&sIn[rr * LDI + sk] = v;
        }
        for (int f4 = tid; f4 < KC * COUT / 4; f4 += 256)
            *(float4*)&sW[f4 * 4] = *(const float4*)&W[(size_t)kc * COUT + f4 * 4];
        __syncthreads();

        for (int kk = 0; kk < KC; kk += 4) {
            float4 a[8];
#pragma unroll
            for (int j = 0; j < 8; ++j)
                a[j] = *(const float4*)&sIn[(tr * 8 + j) * LDI + kk];
#pragma unroll
            for (int t = 0; t < 4; ++t) {
                float4 w0 = *(const float4*)&sW[(kk + t) * COUT + tc * 4];
                float4 w1;
                if constexpr (CT == 8)
                    w1 = *(const float4*)&sW[(kk + t) * COUT + COUT / 2 + tc * 4];
#pragma unroll
                for (int j = 0; j < 8; ++j) {
                    float av = (t == 0) ? a[j].x : (t == 1) ? a[j].y
                             : (t == 2) ? a[j].z : a[j].w;
                    acc[j][0] = fmaf(av, w0.x, acc[j][0]);
                    acc[j][1] = fmaf(av, w0.y, acc[j][1]);
                    acc[j][2] = fmaf(av, w0.z, acc[j][2]);
                    acc[j][3] = fmaf(av, w0.w, acc[j][3]);
                    if constexpr (CT == 8) {
                        acc[j][4] = fmaf(av, w1.x, acc[j][4]);
                        acc[j][5] = fmaf(av, w1.y, acc[j][5]);
                        acc[j][6] = fmaf(av, w1.z, acc[j][6]);
                        acc[j][7] = fmaf(av, w1.w, acc[j][7]);
                    }
                }
            }
        }
        __syncthreads();
    }

#pragma unroll
    for (int j = 0; j < 8; ++j) {
        int gr = row0 + tr * 8 + j;
        if (gr < n) {
            float dv = dinv[gr];
            float4 o0 = {acc[j][0] * dv, acc[j][1] * dv, acc[j][2] * dv, acc[j][3] * dv};
            *(float4*)&out[(size_t)gr * COUT + tc * 4] = o0;
            if constexpr (CT == 8) {
                float4 o1 = {acc[j][4] * dv, acc[j][5] * dv, acc[j][6] * dv, acc[j][7] * dv};
                *(float4*)&out[(size_t)gr * COUT + COUT / 2 + tc * 4] = o1;
            }
        }
    }
}

// heads matmul: out = g3 (N x 64) @ Wcat (64 x 128) + [bmu|bls] -> mu, ls
__global__ __launch_bounds__(256) void k_mm_heads(const float* __restrict__ in,
                                                  const float* __restrict__ W,
                                                  const float* __restrict__ bmu,
                                                  const float* __restrict__ bls,
                                                  float* __restrict__ mu,
                                                  float* __restrict__ ls, int n) {
    constexpr int BM = 128, KC = 32, LDI = KC + 4, K = 64, COUT = 128;
    __shared__ float sIn[BM * LDI];
    __shared__ float sW[KC * COUT];

    const int tid = threadIdx.x;
    const int row0 = blockIdx.x * BM;
    const int tc = tid & 15;
    const int tr = tid >> 4;

    float acc[8][8];
#pragma unroll
    for (int j = 0; j < 8; ++j)
#pragma unroll
        for (int c = 0; c < 8; ++c) acc[j][c] = 0.f;

    const int sr = tid >> 3;
    const int sk = (tid & 7) * 4;

    for (int kc = 0; kc < K; kc += KC) {
#pragma unroll
        for (int p = 0; p < 4; ++p) {
            int rr = p * 32 + sr;
            int gr = row0 + rr;
            float4 v = {0.f, 0.f, 0.f, 0.f};
            if (gr < n) v = *(const float4*)&in[(size_t)gr * K + kc + sk];
            *(float4*)&sIn[rr * LDI + sk] = v;
        }
        for (int f4 = tid; f4 < KC * COUT / 4; f4 += 256)
            *(float4*)&sW[f4 * 4] = *(const float4*)&W[(size_t)kc * COUT + f4 * 4];
        __syncthreads();

        for (int kk = 0; kk < KC; kk += 4) {
            float4 a[8];
#pragma unroll
            for (int j = 0; j < 8; ++j)
                a[j] = *(const float4*)&sIn[(tr * 8 + j) * LDI + kk];
#pragma unroll
            for (int t = 0; t < 4; ++t) {
                float4 w0 = *(const float4*)&sW[(kk + t) * COUT + tc * 4];
                float4 w1 = *(const float4*)&sW[(kk + t) * COUT + 64 + tc * 4];
#pragma unroll
                for (int j = 0; j < 8; ++j) {
                    float av = (t == 0) ? a[j].x : (t == 1) ? a[j].y
                             : (t == 2) ? a[j].z : a[j].w;
                    acc[j][0] = fmaf(av, w0.x, acc[j][0]);
                    acc[j][1] = fmaf(av, w0.y, acc[j][1]);
                    acc[j][2] = fmaf(av, w0.z, acc[j][2]);
                    acc[j][3] = fmaf(av, w0.w, acc[j][3]);
                    acc[j][4] = fmaf(av, w1.x, acc[j][4]);
                    acc[j][5] = fmaf(av, w1.y, acc[j][5]);
                    acc[j][6] = fmaf(av, w1.z, acc[j][6]);
                    acc[j][7] = fmaf(av, w1.w, acc[j][7]);
                }
            }
        }
        __syncthreads();
    }

    float4 bm = ((const float4*)bmu)[tc];
    float4 bl = ((const float4*)bls)[tc];
#pragma unroll
    for (int j = 0; j < 8; ++j) {
        int gr = row0 + tr * 8 + j;
        if (gr < n) {
            float4 o0 = {acc[j][0] + bm.x, acc[j][1] + bm.y, acc[j][2] + bm.z, acc[j][3] + bm.w};
            float4 o1 = {acc[j][4] + bl.x, acc[j][5] + bl.y, acc[j][6] + bl.z, acc[j][7] + bl.w};
            *(float4*)&mu[(size_t)gr * 64 + tc * 4] = o0;
            *(float4*)&ls[(size_t)gr * 64 + tc * 4] = o1;
        }
    }
}

// 128-wide packed gather (layer 2): 32 lanes x float4 = one full row ->
// 2 edges per wave-instruction; 16 edges/iteration, masked. shfl_xor(32).
__global__ __launch_bounds__(256) void k_gather128p(const float* __restrict__ tab,
                                                    const int* __restrict__ rptr,
                                                    const int* __restrict__ col,
                                                    const float* __restrict__ dinv,
                                                    const float* __restrict__ b,
                                                    float* __restrict__ out, int n) {
    const int wave = threadIdx.x >> 6;
    const int lane = threadIdx.x & 63;
    const int g = lane >> 5;
    const int q = lane & 31;
    const int node = blockIdx.x * 4 + wave;
    if (node >= n) return;
    const int beg = rptr[node], end = rptr[node + 1];

    float4 acc = {0.f, 0.f, 0.f, 0.f};
    int j = beg;
    if (j < end) {
        int s[8]; bool val[8];
#pragma unroll
        for (int u = 0; u < 8; ++u) {
            int ei = j + 2 * u + g;
            val[u] = ei < end;
            s[u] = val[u] ? col[ei] : node;
        }
        j += 16;
        while (true) {
            float4 v[8];
#pragma unroll
            for (int u = 0; u < 8; ++u)
                v[u] = *(const float4*)&tab[(size_t)s[u] * 128 + q * 4];
            const bool more = j < end;
            int sn[8]; bool vn[8];
            if (more) {
#pragma unroll
                for (int u = 0; u < 8; ++u) {
                    int ei = j + 2 * u + g;
                    vn[u] = ei < end;
                    sn[u] = vn[u] ? col[ei] : node;
                }
            }
#pragma unroll
            for (int u = 0; u < 8; ++u) {
                if (val[u]) {
                    acc.x += v[u].x; acc.y += v[u].y;
                    acc.z += v[u].z; acc.w += v[u].w;
                }
            }
            if (!more) break;
#pragma unroll
            for (int u = 0; u < 8; ++u) { s[u] = sn[u]; val[u] = vn[u]; }
            j += 16;
        }
    }
    acc.x += __shfl_xor(acc.x, 32, 64); acc.y += __shfl_xor(acc.y, 32, 64);
    acc.z += __shfl_xor(acc.z, 32, 64); acc.w += __shfl_xor(acc.w, 32, 64);

    if (g == 0) {
        float4 self = *(const float4*)&tab[(size_t)node * 128 + q * 4];
        float dn = dinv[node];
        float4 bb = ((const float4*)b)[q];
        float4 o = {(acc.x + self.x) * dn + bb.x, (acc.y + self.y) * dn + bb.y,
                    (acc.z + self.z) * dn + bb.z, (acc.w + self.w) * dn + bb.w};
        *(float4*)&out[(size_t)node * 128 + q * 4] = o;
    }
}

// 64-wide packed gather: 16 lanes x float4 = one full row -> 4 edges/instr.
// MODE 1: out = dn*relu(o + b)  (layer 3);  MODE 2: out = o  (head pre-gather)
template <int MODE>
__global__ __launch_bounds__(256) void k_gather64p(const float* __restrict__ tab,
                                                   const int* __restrict__ rptr,
                                                   const int* __restrict__ col,
                                                   const float* __restrict__ dinv,
                                                   const float* __restrict__ b,
                                                   float* __restrict__ out, int n) {
    const int wave = threadIdx.x >> 6;
    const int lane = threadIdx.x & 63;
    const int g = lane >> 4;
    const int q = lane & 15;
    const int node = blockIdx.x * 4 + wave;
    if (node >= n) return;
    const int beg = rptr[node], end = rptr[node + 1];

    float4 acc = {0.f, 0.f, 0.f, 0.f};
    int j = beg;
    if (j < end) {
        int s[4]; bool val[4];
#pragma unroll
        for (int u = 0; u < 4; ++u) {
            int ei = j + 4 * u + g;
            val[u] = ei < end;
            s[u] = val[u] ? col[ei] : node;
        }
        j += 16;
        while (true) {
            float4 v[4];
#pragma unroll
            for (int u = 0; u < 4; ++u)
                v[u] = *(const float4*)&tab[(size_t)s[u] * 64 + q * 4];
            const bool more = j < end;
            int sn[4]; bool vn[4];
            if (more) {
#pragma unroll
                for (int u = 0; u < 4; ++u) {
                    int ei = j + 4 * u + g;
                    vn[u] = ei < end;
                    sn[u] = vn[u] ? col[ei] : node;
                }
            }
#pragma unroll
            for (int u = 0; u < 4; ++u) {
                if (val[u]) {
                    acc.x += v[u].x; acc.y += v[u].y;
                    acc.z += v[u].z; acc.w += v[u].w;
                }
            }
            if (!more) break;
#pragma unroll
            for (int u = 0; u < 4; ++u) { s[u] = sn[u]; val[u] = vn[u]; }
            j += 16;
        }
    }
    acc.x += __shfl_xor(acc.x, 16, 64); acc.y += __shfl_xor(acc.y, 16, 64);
    acc.z += __shfl_xor(acc.z, 16, 64); acc.w += __shfl_xor(acc.w, 16, 64);
    acc.x += __shfl_xor(acc.x, 32, 64); acc.y += __shfl_xor(acc.y, 32, 64);
    acc.z += __shfl_xor(acc.z, 32, 64); acc.w += __shfl_xor(acc.w, 32, 64);

    if (g == 0) {
        float4 self = *(const float4*)&tab[(size_t)node * 64 + q * 4];
        float dn = dinv[node];
        float4 o = {(acc.x + self.x) * dn, (acc.y + self.y) * dn,
                    (acc.z + self.z) * dn, (acc.w + self.w) * dn};
        if constexpr (MODE == 1) {
            float4 bb = ((const float4*)b)[q];
            o.x = fmaxf(o.x + bb.x, 0.f) * dn;
            o.y = fmaxf(o.y + bb.y, 0.f) * dn;
            o.z = fmaxf(o.z + bb.z, 0.f) * dn;
            o.w = fmaxf(o.w + bb.w, 0.f) * dn;
        }
        *(float4*)&out[(size_t)node * 64 + q * 4] = o;
    }
}

extern "C" void kernel_launch(void* const* d_in, const int* in_sizes, int n_in,
                              void* d_out, int out_size, void* d_ws, size_t ws_size,
                              hipStream_t stream) {
    const int*   x    = (const int*)d_in[0];
    const int*   ei   = (const int*)d_in[1];
    const float* embW = (const float*)d_in[2];
    const float* W1   = (const float*)d_in[3];
    const float* b1   = (const float*)d_in[4];
    const float* W2   = (const float*)d_in[5];
    const float* b2   = (const float*)d_in[6];
    const float* W3   = (const float*)d_in[7];
    const float* b3   = (const float*)d_in[8];
    const float* Wmu  = (const float*)d_in[9];
    const float* bmu  = (const float*)d_in[10];
    const float* Wls  = (const float*)d_in[11];
    const float* bls  = (const float*)d_in[12];

    const int n = in_sizes[0];
    const int e = in_sizes[1] / 2;
    const int V = in_sizes[2] / 128;
    const int* src = ei;
    const int* dst = ei + e;

    char* w = (char*)d_ws;
    auto alloc = [&](size_t bytes) {
        char* p = w;
        w += (bytes + 255) & ~(size_t)255;
        return p;
    };
    float* bufA = (float*)alloc((size_t)n * 128 * 4);
    float* bufB = (float*)alloc((size_t)n * 128 * 4);
    float* hW   = (float*)alloc((size_t)n * 128 * 4);
    int*   rptr = (int*)alloc((size_t)(n + 1) * 4);
    int*   col  = (int*)alloc((size_t)e * 4);
    int*   pck  = (int*)alloc((size_t)e * 4);
    float* dinv = (float*)alloc((size_t)n * 4);
    int2*  xd   = (int2*)alloc((size_t)n * 8);
    float* Wcat = (float*)alloc((size_t)64 * 128 * 4);
    float* Msm  = (float*)alloc((size_t)32 * 128 * 4);
    int*   boff = (int*)alloc((size_t)257 * 4);
    int*   bsum = (int*)alloc((size_t)256 * 4);

    const int ntile = (e + 4095) / 4096;
    const int nbuck = (n + 255) / 256;
    int* hist_g = (int*)alloc((size_t)ntile * 256 * 4);
    int* tbase  = (int*)alloc((size_t)ntile * 256 * 4);

    const int nsm = (V + 1) / 2;

    // ---- atomic-free CSR build (reused by all layers) ----
    k_hist  <<<ntile, 256, 0, stream>>>(dst, hist_g, e);
    k_scanT <<<256, 256, 0, stream>>>(hist_g, tbase, bsum, ntile);
    k_bscan2<<<1, 256, 0, stream>>>(bsum, boff);
    k_binA3 <<<ntile, 256, 0, stream>>>(src, dst, boff, tbase, pck, e);
    k_binB2 <<<nbuck, 256, 0, stream>>>(pck, boff, x, rptr, dinv, xd, col, n);
    k_prepW <<<nsm + 32, 256, 0, stream>>>(embW, W1, Wmu, Wls, Msm, Wcat, V, nsm);

    const int gmm = (n + 127) / 128;
    const int ggt = (n + 3) / 4;
    float* mu = (float*)d_out;
    float* ls = (float*)d_out + (size_t)n * 64;

    // layer 1: 28-row LDS-table gather
    k_gather_l1<<<ggt, 256, 0, stream>>>(Msm, rptr, col, xd, b1, bufA, n, V);
    // layer 2: matmul (relu on load) + packed 128-wide gather
    k_matmul<128, 128, true><<<gmm, 256, 0, stream>>>(bufA, W2, dinv, hW, n);
    k_gather128p<<<ggt, 256, 0, stream>>>(hW, rptr, col, dinv, b2, bufB, n);
    // layer 3: matmul 128->64 + packed 64-wide gather, out = dinv*relu(conv3)
    k_matmul<128, 64, true><<<gmm, 256, 0, stream>>>(bufB, W3, dinv, hW, n);
    k_gather64p<1><<<ggt, 256, 0, stream>>>(hW, rptr, col, dinv, b3, bufA, n);
    // heads: g3 = A*(dinv*relu(conv3)) packed gather, then 64->128 matmul
    k_gather64p<2><<<ggt, 256, 0, stream>>>(bufA, rptr, col, dinv, bmu, bufB, n);
    k_mm_heads<<<gmm, 256, 0, stream>>>(bufB, Wcat, bmu, bls, mu, ls, n);
}

// Round 13
// 261.954 us; speedup vs baseline: 1.3133x; 1.0343x over previous
//
#include <hip/hip_runtime.h>
#include <hip/hip_bf16.h>
#include <cstddef>

// ---------------------------------------------------------------------------
// GCN variational encoder: N nodes, E edges, H=128 hidden, C=64 out.
// A(HW) = (AH)W lets each layer gather in the narrow domain.
// Gathers: per-VMEM-instruction packed; 128-wide gather sits at the random
// 64B-line L2-fill fabric ceiling (~186MB @ ~3.8TB/s) -- accepted floor.
// CSR build: atomic-free 3-phase; binB2 at 1024 thr/block (was 1 blk/CU @
// 4 waves = 12.5% occupancy). Matmuls: A-tile register prefetch.
// ---------------------------------------------------------------------------

// ---- CSR pipeline (bucket = dst>>8; requires n <= 65536) ----

__global__ __launch_bounds__(256) void k_hist(const int* __restrict__ dst,
                                              int* __restrict__ hist_g, int e) {
    __shared__ int h[256];
    const int tid = threadIdx.x;
    h[tid] = 0;
    __syncthreads();
    const int e0 = blockIdx.x * 4096;
    const int e1 = min(e0 + 4096, e);
    for (int j = e0 + tid; j < e1; j += 256) atomicAdd(&h[dst[j] >> 8], 1);
    __syncthreads();
    hist_g[blockIdx.x * 256 + tid] = h[tid];
}

// one block per bucket: parallel scan over tiles -> tbase; total -> bsum
__global__ __launch_bounds__(256) void k_scanT(const int* __restrict__ hist_g,
                                               int* __restrict__ tbase,
                                               int* __restrict__ bsum, int ntile) {
    const int b = blockIdx.x;
    const int t = threadIdx.x;
    const int lane = t & 63, wv = t >> 6;
    __shared__ int wsum[4];
    int carry = 0;
    for (int c = 0; c < ntile; c += 256) {
        int tt = c + t;
        int v0 = (tt < ntile) ? hist_g[tt * 256 + b] : 0;
        int v = v0;
#pragma unroll
        for (int d = 1; d < 64; d <<= 1) {
            int w = __shfl_up(v, d, 64);
            if (lane >= d) v += w;
        }
        if (lane == 63) wsum[wv] = v;
        __syncthreads();
        int woff = 0;
        for (int w = 0; w < wv; ++w) woff += wsum[w];
        int tot = wsum[0] + wsum[1] + wsum[2] + wsum[3];
        if (tt < ntile) tbase[tt * 256 + b] = carry + woff + v - v0;
        carry += tot;
        __syncthreads();
    }
    if (t == 0) bsum[b] = carry;
}

// single block: exclusive scan bsum[256] -> boff[257]
__global__ __launch_bounds__(256) void k_bscan2(const int* __restrict__ bsum,
                                                int* __restrict__ boff) {
    __shared__ int wsum[4];
    const int t = threadIdx.x;
    const int lane = t & 63, wv = t >> 6;
    int v0 = bsum[t];
    int v = v0;
#pragma unroll
    for (int d = 1; d < 64; d <<= 1) {
        int w = __shfl_up(v, d, 64);
        if (lane >= d) v += w;
    }
    if (lane == 63) wsum[wv] = v;
    __syncthreads();
    int woff = 0;
    for (int w = 0; w < wv; ++w) woff += wsum[w];
    int excl = woff + v - v0;
    boff[t] = excl;
    if (t == 255) boff[256] = excl + v0;
}

// single-pass scatter: packed (dlocal<<16 | src) at boff[b]+tbase[tile][b]+rank
__global__ __launch_bounds__(256) void k_binA3(const int* __restrict__ src,
                                               const int* __restrict__ dst,
                                               const int* __restrict__ boff,
                                               const int* __restrict__ tbase,
                                               int* __restrict__ packed, int e) {
    __shared__ int hist[256];
    __shared__ int base[256];
    const int tid = threadIdx.x;
    const int e0 = blockIdx.x * 4096;
    const int e1 = min(e0 + 4096, e);
    hist[tid] = 0;
    base[tid] = boff[tid] + tbase[blockIdx.x * 256 + tid];
    __syncthreads();
    for (int j = e0 + tid; j < e1; j += 256) {
        int d = dst[j];
        int b = d >> 8;
        int r = atomicAdd(&hist[b], 1);
        packed[base[b] + r] = ((d & 255) << 16) | src[j];
    }
}

// per bucket (1024 threads): node hist + scan -> rptr/dinv/xd; LDS sort -> col
#define BCAP 6144
__global__ __launch_bounds__(1024) void k_binB2(const int* __restrict__ packed,
                                                const int* __restrict__ boff,
                                                const int* __restrict__ x,
                                                int* __restrict__ rptr,
                                                float* __restrict__ dinv,
                                                int2* __restrict__ xd,
                                                int* __restrict__ col,
                                                int n) {
    __shared__ int hist[256];
    __shared__ int cur[256];
    __shared__ int wsum[4];
    __shared__ int buf[BCAP];
    const int tid = threadIdx.x;
    const int node0 = blockIdx.x << 8;
    const int node1 = min(node0 + 256, n);
    const int ebeg = boff[blockIdx.x];
    const int eend = boff[blockIdx.x + 1];
    const int cnt = eend - ebeg;

    if (tid < 256) hist[tid] = 0;
    __syncthreads();
    for (int j = tid; j < cnt; j += 1024) atomicAdd(&hist[packed[ebeg + j] >> 16], 1);
    __syncthreads();

    int deg = 0, v = 0;
    if (tid < 256) {
        const int lane = tid & 63, wv = tid >> 6;
        deg = hist[tid];
        v = deg;
#pragma unroll
        for (int d = 1; d < 64; d <<= 1) {
            int w = __shfl_up(v, d, 64);
            if (lane >= d) v += w;
        }
        if (lane == 63) wsum[wv] = v;
    }
    __syncthreads();
    if (tid < 256) {
        const int wv = tid >> 6;
        int woff = 0;
        for (int w = 0; w < wv; ++w) woff += wsum[w];
        const int excl = woff + v - deg;
        cur[tid] = excl;
        const int node = node0 + tid;
        if (node < node1) {
            rptr[node] = ebeg + excl;
            float dv = 1.0f / sqrtf((float)(deg + 1));
            dinv[node] = dv;
            xd[node] = make_int2(x[node], __float_as_int(dv));
        }
        if (node1 == n && tid == 0) rptr[n] = eend;
    }
    __syncthreads();

    if (cnt <= BCAP) {
        for (int j = tid; j < cnt; j += 1024) {
            int p = packed[ebeg + j];
            int pos = atomicAdd(&cur[p >> 16], 1);
            buf[pos] = p & 0xffff;
        }
        __syncthreads();
        for (int j = tid; j < cnt; j += 1024) col[ebeg + j] = buf[j];
    } else {
        for (int j = tid; j < cnt; j += 1024) {
            int p = packed[ebeg + j];
            int pos = atomicAdd(&cur[p >> 16], 1);
            col[ebeg + pos] = p & 0xffff;
        }
    }
}

// fused weight prep: blocks [0,nsm): M = embW @ W1 (2 rows/block);
// blocks [nsm, nsm+32): Wcat[k*128+c] = c<64 ? Wmu[k][c] : Wls[k][c-64]
__global__ __launch_bounds__(256) void k_prepW(const float* __restrict__ embW,
                                               const float* __restrict__ W1,
                                               const float* __restrict__ Wmu,
                                               const float* __restrict__ Wls,
                                               float* __restrict__ M,
                                               float* __restrict__ Wcat,
                                               int V, int nsm) {
    if ((int)blockIdx.x < nsm) {
        const int r = blockIdx.x * 2 + (threadIdx.x >> 7);
        const int c = threadIdx.x & 127;
        if (r >= V) return;
        float a0 = 0.f, a1 = 0.f;
        const float* er = embW + (size_t)r * 128;
#pragma unroll 4
        for (int k = 0; k < 128; k += 2) {
            a0 = fmaf(er[k], W1[(size_t)k * 128 + c], a0);
            a1 = fmaf(er[k + 1], W1[(size_t)(k + 1) * 128 + c], a1);
        }
        M[(size_t)r * 128 + c] = a0 + a1;
    } else {
        int i = (blockIdx.x - nsm) * 256 + threadIdx.x;
        if (i < 64 * 128) {
            int k = i >> 7, c = i & 127;
            Wcat[i] = (c < 64) ? Wmu[k * 64 + c] : Wls[k * 64 + (c - 64)];
        }
    }
}

// layer-1 gather: M table (V<=32 rows x 128) in LDS; per edge read packed
// xd[s]={x,dinv} (8B, L2-resident) and accumulate dinv * M[x].
__global__ __launch_bounds__(256) void k_gather_l1(const float* __restrict__ M,
                                                   const int* __restrict__ rptr,
                                                   const int* __restrict__ col,
                                                   const int2* __restrict__ xd,
                                                   const float* __restrict__ b,
                                                   float* __restrict__ out,
                                                   int n, int V) {
    __shared__ float sh[32 * 128];
    for (int f = threadIdx.x; f < V * 32; f += 256)
        ((float4*)sh)[f] = ((const float4*)M)[f];
    __syncthreads();

    const int wave = threadIdx.x >> 6;
    const int lane = threadIdx.x & 63;
    const int node = blockIdx.x * 4 + wave;
    if (node >= n) return;
    const int beg = rptr[node], end = rptr[node + 1];
    int j = beg;

    float ax0 = 0.f, ay0 = 0.f, ax1 = 0.f, ay1 = 0.f;
    const int lo = 2 * lane;
    if (end - beg >= 8) {
        int s[8];
#pragma unroll
        for (int u = 0; u < 8; ++u) s[u] = col[j + u];
        j += 8;
        while (true) {
            int2 p[8];
#pragma unroll
            for (int u = 0; u < 8; ++u) p[u] = xd[s[u]];
            const bool more = (j + 8 <= end);
            int sn[8];
            if (more) {
#pragma unroll
                for (int u = 0; u < 8; ++u) sn[u] = col[j + u];
            }
#pragma unroll
            for (int u = 0; u < 8; ++u) {
                float dv = __int_as_float(p[u].y);
                float2 v = *(const float2*)&sh[p[u].x * 128 + lo];
                if (u & 1) { ax1 = fmaf(dv, v.x, ax1); ay1 = fmaf(dv, v.y, ay1); }
                else       { ax0 = fmaf(dv, v.x, ax0); ay0 = fmaf(dv, v.y, ay0); }
            }
            if (!more) break;
#pragma unroll
            for (int u = 0; u < 8; ++u) s[u] = sn[u];
            j += 8;
        }
    }
    for (; j < end; ++j) {
        int2 p = xd[col[j]];
        float dv = __int_as_float(p.y);
        float2 v = *(const float2*)&sh[p.x * 128 + lo];
        ax0 = fmaf(dv, v.x, ax0); ay0 = fmaf(dv, v.y, ay0);
    }
    int2 pn = xd[node];
    float dn = __int_as_float(pn.y);
    float2 sv = *(const float2*)&sh[pn.x * 128 + lo];
    float2 bb = ((const float2*)b)[lane];
    float ox = (ax0 + ax1 + dn * sv.x) * dn + bb.x;
    float oy = (ay0 + ay1 + dn * sv.y) * dn + bb.y;
    ((float2*)out)[(size_t)node * 64 + lane] = {ox, oy};
}

// out[r][c] = dinv[r] * sum_k act(in[r][k]) * W[k][c]
// BM=128, KC=32; A-tile register-prefetched across chunks.
template <int K, int COUT, bool RELU>
__global__ __launch_bounds__(256) void k_matmul(const float* __restrict__ in,
                                                const float* __restrict__ W,
                                                const float* __restrict__ dinv,
                                                float* __restrict__ out, int n) {
    constexpr int BM = 128, KC = 32, LDI = KC + 4;
    constexpr int CT = COUT / 16;
    __shared__ float sIn[BM * LDI];
    __shared__ float sW[KC * COUT];

    const int tid = threadIdx.x;
    const int row0 = blockIdx.x * BM;
    const int tc = tid & 15;
    const int tr = tid >> 4;

    float acc[8][CT];
#pragma unroll
    for (int j = 0; j < 8; ++j)
#pragma unroll
        for (int c = 0; c < CT; ++c) acc[j][c] = 0.f;

    const int sr = tid >> 3;
    const int sk = (tid & 7) * 4;

    // prefetch chunk 0 A-tile into registers
    float4 pf[4];
#pragma unroll
    for (int p = 0; p < 4; ++p) {
        int gr = row0 + p * 32 + sr;
        pf[p] = (gr < n) ? *(const float4*)&in[(size_t)gr * K + sk]
                         : float4{0.f, 0.f, 0.f, 0.f};
    }

    for (int kc = 0; kc < K; kc += KC) {
        // store prefetched A-tile (act on store)
#pragma unroll
        for (int p = 0; p < 4; ++p) {
            float4 v = pf[p];
            if (RELU) {
                v.x = fmaxf(v.x, 0.f); v.y = fmaxf(v.y, 0.f);
                v.z = fmaxf(v.z, 0.f); v.w = fmaxf(v.w, 0.f);
            }
            *(float4*)&sIn[(p * 32 + sr) * LDI + sk] = v;
        }
        for (int f4 = tid; f4 < KC * COUT / 4; f4 += 256)
            *(float4*)&sW[f4 * 4] = *(const float4*)&W[(size_t)kc * COUT + f4 * 4];
        __syncthreads();

        // issue next chunk's A-loads (fly during compute)
        if (kc + KC < K) {
#pragma unroll
            for (int p = 0; p < 4; ++p) {
                int gr = row0 + p * 32 + sr;
                pf[p] = (gr < n) ? *(const float4*)&in[(size_t)gr * K + kc + KC + sk]
                                 : float4{0.f, 0.f, 0.f, 0.f};
            }
        }

        for (int kk = 0; kk < KC; kk += 4) {
            float4 a[8];
#pragma unroll
            for (int j = 0; j < 8; ++j)
                a[j] = *(const float4*)&sIn[(tr * 8 + j) * LDI + kk];
#pragma unroll
            for (int t = 0; t < 4; ++t) {
                float4 w0 = *(const float4*)&sW[(kk + t) * COUT + tc * 4];
                float4 w1;
                if constexpr (CT == 8)
                    w1 = *(const float4*)&sW[(kk + t) * COUT + COUT / 2 + tc * 4];
#pragma unroll
                for (int j = 0; j < 8; ++j) {
                    float av = (t == 0) ? a[j].x : (t == 1) ? a[j].y
                             : (t == 2) ? a[j].z : a[j].w;
                    acc[j][0] = fmaf(av, w0.x, acc[j][0]);
                    acc[j][1] = fmaf(av, w0.y, acc[j][1]);
                    acc[j][2] = fmaf(av, w0.z, acc[j][2]);
                    acc[j][3] = fmaf(av, w0.w, acc[j][3]);
                    if constexpr (CT == 8) {
                        acc[j][4] = fmaf(av, w1.x, acc[j][4]);
                        acc[j][5] = fmaf(av, w1.y, acc[j][5]);
                        acc[j][6] = fmaf(av, w1.z, acc[j][6]);
                        acc[j][7] = fmaf(av, w1.w, acc[j][7]);
                    }
                }
            }
        }
        __syncthreads();
    }

#pragma unroll
    for (int j = 0; j < 8; ++j) {
        int gr = row0 + tr * 8 + j;
        if (gr < n) {
            float dv = dinv[gr];
            float4 o0 = {acc[j][0] * dv, acc[j][1] * dv, acc[j][2] * dv, acc[j][3] * dv};
            *(float4*)&out[(size_t)gr * COUT + tc * 4] = o0;
            if constexpr (CT == 8) {
                float4 o1 = {acc[j][4] * dv, acc[j][5] * dv, acc[j][6] * dv, acc[j][7] * dv};
                *(float4*)&out[(size_t)gr * COUT + COUT / 2 + tc * 4] = o1;
            }
        }
    }
}

// heads matmul: out = g3 (N x 64) @ Wcat (64 x 128) + [bmu|bls] -> mu, ls
__global__ __launch_bounds__(256) void k_mm_heads(const float* __restrict__ in,
                                                  const float* __restrict__ W,
                                                  const float* __restrict__ bmu,
                                                  const float* __restrict__ bls,
                                                  float* __restrict__ mu,
                                                  float* __restrict__ ls, int n) {
    constexpr int BM = 128, KC = 32, LDI = KC + 4, K = 64, COUT = 128;
    __shared__ float sIn[BM * LDI];
    __shared__ float sW[KC * COUT];

    const int tid = threadIdx.x;
    const int row0 = blockIdx.x * BM;
    const int tc = tid & 15;
    const int tr = tid >> 4;

    float acc[8][8];
#pragma unroll
    for (int j = 0; j < 8; ++j)
#pragma unroll
        for (int c = 0; c < 8; ++c) acc[j][c] = 0.f;

    const int sr = tid >> 3;
    const int sk = (tid & 7) * 4;

    float4 pf[4];
#pragma unroll
    for (int p = 0; p < 4; ++p) {
        int gr = row0 + p * 32 + sr;
        pf[p] = (gr < n) ? *(const float4*)&in[(size_t)gr * K + sk]
                         : float4{0.f, 0.f, 0.f, 0.f};
    }

    for (int kc = 0; kc < K; kc += KC) {
#pragma unroll
        for (int p = 0; p < 4; ++p)
            *(float4*)&sIn[(p * 32 + sr) * LDI + sk] = pf[p];
        for (int f4 = tid; f4 < KC * COUT / 4; f4 += 256)
            *(float4*)&sW[f4 * 4] = *(const float4*)&W[(size_t)kc * COUT + f4 * 4];
        __syncthreads();

        if (kc + KC < K) {
#pragma unroll
            for (int p = 0; p < 4; ++p) {
                int gr = row0 + p * 32 + sr;
                pf[p] = (gr < n) ? *(const float4*)&in[(size_t)gr * K + kc + KC + sk]
                                 : float4{0.f, 0.f, 0.f, 0.f};
            }
        }

        for (int kk = 0; kk < KC; kk += 4) {
            float4 a[8];
#pragma unroll
            for (int j = 0; j < 8; ++j)
                a[j] = *(const float4*)&sIn[(tr * 8 + j) * LDI + kk];
#pragma unroll
            for (int t = 0; t < 4; ++t) {
                float4 w0 = *(const float4*)&sW[(kk + t) * COUT + tc * 4];
                float4 w1 = *(const float4*)&sW[(kk + t) * COUT + 64 + tc * 4];
#pragma unroll
                for (int j = 0; j < 8; ++j) {
                    float av = (t == 0) ? a[j].x : (t == 1) ? a[j].y
                             : (t == 2) ? a[j].z : a[j].w;
                    acc[j][0] = fmaf(av, w0.x, acc[j][0]);
                    acc[j][1] = fmaf(av, w0.y, acc[j][1]);
                    acc[j][2] = fmaf(av, w0.z, acc[j][2]);
                    acc[j][3] = fmaf(av, w0.w, acc[j][3]);
                    acc[j][4] = fmaf(av, w1.x, acc[j][4]);
                    acc[j][5] = fmaf(av, w1.y, acc[j][5]);
                    acc[j][6] = fmaf(av, w1.z, acc[j][6]);
                    acc[j][7] = fmaf(av, w1.w, acc[j][7]);
                }
            }
        }
        __syncthreads();
    }

    float4 bm = ((const float4*)bmu)[tc];
    float4 bl = ((const float4*)bls)[tc];
#pragma unroll
    for (int j = 0; j < 8; ++j) {
        int gr = row0 + tr * 8 + j;
        if (gr < n) {
            float4 o0 = {acc[j][0] + bm.x, acc[j][1] + bm.y, acc[j][2] + bm.z, acc[j][3] + bm.w};
            float4 o1 = {acc[j][4] + bl.x, acc[j][5] + bl.y, acc[j][6] + bl.z, acc[j][7] + bl.w};
            *(float4*)&mu[(size_t)gr * 64 + tc * 4] = o0;
            *(float4*)&ls[(size_t)gr * 64 + tc * 4] = o1;
        }
    }
}

// 128-wide packed gather (layer 2): 32 lanes x float4 = one full row ->
// 2 edges per wave-instruction; 16 edges/iteration, masked. shfl_xor(32).
__global__ __launch_bounds__(256) void k_gather128p(const float* __restrict__ tab,
                                                    const int* __restrict__ rptr,
                                                    const int* __restrict__ col,
                                                    const float* __restrict__ dinv,
                                                    const float* __restrict__ b,
                                                    float* __restrict__ out, int n) {
    const int wave = threadIdx.x >> 6;
    const int lane = threadIdx.x & 63;
    const int g = lane >> 5;
    const int q = lane & 31;
    const int node = blockIdx.x * 4 + wave;
    if (node >= n) return;
    const int beg = rptr[node], end = rptr[node + 1];

    float4 acc = {0.f, 0.f, 0.f, 0.f};
    int j = beg;
    if (j < end) {
        int s[8]; bool val[8];
#pragma unroll
        for (int u = 0; u < 8; ++u) {
            int ei = j + 2 * u + g;
            val[u] = ei < end;
            s[u] = val[u] ? col[ei] : node;
        }
        j += 16;
        while (true) {
            float4 v[8];
#pragma unroll
            for (int u = 0; u < 8; ++u)
                v[u] = *(const float4*)&tab[(size_t)s[u] * 128 + q * 4];
            const bool more = j < end;
            int sn[8]; bool vn[8];
            if (more) {
#pragma unroll
                for (int u = 0; u < 8; ++u) {
                    int ei = j + 2 * u + g;
                    vn[u] = ei < end;
                    sn[u] = vn[u] ? col[ei] : node;
                }
            }
#pragma unroll
            for (int u = 0; u < 8; ++u) {
                if (val[u]) {
                    acc.x += v[u].x; acc.y += v[u].y;
                    acc.z += v[u].z; acc.w += v[u].w;
                }
            }
            if (!more) break;
#pragma unroll
            for (int u = 0; u < 8; ++u) { s[u] = sn[u]; val[u] = vn[u]; }
            j += 16;
        }
    }
    acc.x += __shfl_xor(acc.x, 32, 64); acc.y += __shfl_xor(acc.y, 32, 64);
    acc.z += __shfl_xor(acc.z, 32, 64); acc.w += __shfl_xor(acc.w, 32, 64);

    if (g == 0) {
        float4 self = *(const float4*)&tab[(size_t)node * 128 + q * 4];
        float dn = dinv[node];
        float4 bb = ((const float4*)b)[q];
        float4 o = {(acc.x + self.x) * dn + bb.x, (acc.y + self.y) * dn + bb.y,
                    (acc.z + self.z) * dn + bb.z, (acc.w + self.w) * dn + bb.w};
        *(float4*)&out[(size_t)node * 128 + q * 4] = o;
    }
}

// 64-wide packed gather: 16 lanes x float4 = one full row -> 4 edges/instr.
// MODE 1: out = dn*relu(o + b)  (layer 3);  MODE 2: out = o  (head pre-gather)
template <int MODE>
__global__ __launch_bounds__(256) void k_gather64p(const float* __restrict__ tab,
                                                   const int* __restrict__ rptr,
                                                   const int* __restrict__ col,
                                                   const float* __restrict__ dinv,
                                                   const float* __restrict__ b,
                                                   float* __restrict__ out, int n) {
    const int wave = threadIdx.x >> 6;
    const int lane = threadIdx.x & 63;
    const int g = lane >> 4;
    const int q = lane & 15;
    const int node = blockIdx.x * 4 + wave;
    if (node >= n) return;
    const int beg = rptr[node], end = rptr[node + 1];

    float4 acc = {0.f, 0.f, 0.f, 0.f};
    int j = beg;
    if (j < end) {
        int s[4]; bool val[4];
#pragma unroll
        for (int u = 0; u < 4; ++u) {
            int ei = j + 4 * u + g;
            val[u] = ei < end;
            s[u] = val[u] ? col[ei] : node;
        }
        j += 16;
        while (true) {
            float4 v[4];
#pragma unroll
            for (int u = 0; u < 4; ++u)
                v[u] = *(const float4*)&tab[(size_t)s[u] * 64 + q * 4];
            const bool more = j < end;
            int sn[4]; bool vn[4];
            if (more) {
#pragma unroll
                for (int u = 0; u < 4; ++u) {
                    int ei = j + 4 * u + g;
                    vn[u] = ei < end;
                    sn[u] = vn[u] ? col[ei] : node;
                }
            }
#pragma unroll
            for (int u = 0; u < 4; ++u) {
                if (val[u]) {
                    acc.x += v[u].x; acc.y += v[u].y;
                    acc.z += v[u].z; acc.w += v[u].w;
                }
            }
            if (!more) break;
#pragma unroll
            for (int u = 0; u < 4; ++u) { s[u] = sn[u]; val[u] = vn[u]; }
            j += 16;
        }
    }
    acc.x += __shfl_xor(acc.x, 16, 64); acc.y += __shfl_xor(acc.y, 16, 64);
    acc.z += __shfl_xor(acc.z, 16, 64); acc.w += __shfl_xor(acc.w, 16, 64);
    acc.x += __shfl_xor(acc.x, 32, 64); acc.y += __shfl_xor(acc.y, 32, 64);
    acc.z += __shfl_xor(acc.z, 32, 64); acc.w += __shfl_xor(acc.w, 32, 64);

    if (g == 0) {
        float4 self = *(const float4*)&tab[(size_t)node * 64 + q * 4];
        float dn = dinv[node];
        float4 o = {(acc.x + self.x) * dn, (acc.y + self.y) * dn,
                    (acc.z + self.z) * dn, (acc.w + self.w) * dn};
        if constexpr (MODE == 1) {
            float4 bb = ((const float4*)b)[q];
            o.x = fmaxf(o.x + bb.x, 0.f) * dn;
            o.y = fmaxf(o.y + bb.y, 0.f) * dn;
            o.z = fmaxf(o.z + bb.z, 0.f) * dn;
            o.w = fmaxf(o.w + bb.w, 0.f) * dn;
        }
        *(float4*)&out[(size_t)node * 64 + q * 4] = o;
    }
}

extern "C" void kernel_launch(void* const* d_in, const int* in_sizes, int n_in,
                              void* d_out, int out_size, void* d_ws, size_t ws_size,
                              hipStream_t stream) {
    const int*   x    = (const int*)d_in[0];
    const int*   ei   = (const int*)d_in[1];
    const float* embW = (const float*)d_in[2];
    const float* W1   = (const float*)d_in[3];
    const float* b1   = (const float*)d_in[4];
    const float* W2   = (const float*)d_in[5];
    const float* b2   = (const float*)d_in[6];
    const float* W3   = (const float*)d_in[7];
    const float* b3   = (const float*)d_in[8];
    const float* Wmu  = (const float*)d_in[9];
    const float* bmu  = (const float*)d_in[10];
    const float* Wls  = (const float*)d_in[11];
    const float* bls  = (const float*)d_in[12];

    const int n = in_sizes[0];
    const int e = in_sizes[1] / 2;
    const int V = in_sizes[2] / 128;
    const int* src = ei;
    const int* dst = ei + e;

    char* w = (char*)d_ws;
    auto alloc = [&](size_t bytes) {
        char* p = w;
        w += (bytes + 255) & ~(size_t)255;
        return p;
    };
    float* bufA = (float*)alloc((size_t)n * 128 * 4);
    float* bufB = (float*)alloc((size_t)n * 128 * 4);
    float* hW   = (float*)alloc((size_t)n * 128 * 4);
    int*   rptr = (int*)alloc((size_t)(n + 1) * 4);
    int*   col  = (int*)alloc((size_t)e * 4);
    int*   pck  = (int*)alloc((size_t)e * 4);
    float* dinv = (float*)alloc((size_t)n * 4);
    int2*  xd   = (int2*)alloc((size_t)n * 8);
    float* Wcat = (float*)alloc((size_t)64 * 128 * 4);
    float* Msm  = (float*)alloc((size_t)32 * 128 * 4);
    int*   boff = (int*)alloc((size_t)257 * 4);
    int*   bsum = (int*)alloc((size_t)256 * 4);

    const int ntile = (e + 4095) / 4096;
    const int nbuck = (n + 255) / 256;
    int* hist_g = (int*)alloc((size_t)ntile * 256 * 4);
    int* tbase  = (int*)alloc((size_t)ntile * 256 * 4);

    const int nsm = (V + 1) / 2;

    // ---- atomic-free CSR build (reused by all layers) ----
    k_hist  <<<ntile, 256, 0, stream>>>(dst, hist_g, e);
    k_scanT <<<256, 256, 0, stream>>>(hist_g, tbase, bsum, ntile);
    k_bscan2<<<1, 256, 0, stream>>>(bsum, boff);
    k_binA3 <<<ntile, 256, 0, stream>>>(src, dst, boff, tbase, pck, e);
    k_binB2 <<<nbuck, 1024, 0, stream>>>(pck, boff, x, rptr, dinv, xd, col, n);
    k_prepW <<<nsm + 32, 256, 0, stream>>>(embW, W1, Wmu, Wls, Msm, Wcat, V, nsm);

    const int gmm = (n + 127) / 128;
    const int ggt = (n + 3) / 4;
    float* mu = (float*)d_out;
    float* ls = (float*)d_out + (size_t)n * 64;

    // layer 1: 28-row LDS-table gather
    k_gather_l1<<<ggt, 256, 0, stream>>>(Msm, rptr, col, xd, b1, bufA, n, V);
    // layer 2: matmul (relu on load) + packed 128-wide gather
    k_matmul<128, 128, true><<<gmm, 256, 0, stream>>>(bufA, W2, dinv, hW, n);
    k_gather128p<<<ggt, 256, 0, stream>>>(hW, rptr, col, dinv, b2, bufB, n);
    // layer 3: matmul 128->64 + packed 64-wide gather, out = dinv*relu(conv3)
    k_matmul<128, 64, true><<<gmm, 256, 0, stream>>>(bufB, W3, dinv, hW, n);
    k_gather64p<1><<<ggt, 256, 0, stream>>>(hW, rptr, col, dinv, b3, bufA, n);
    // heads: g3 = A*(dinv*relu(conv3)) packed gather, then 64->128 matmul
    k_gather64p<2><<<ggt, 256, 0, stream>>>(bufA, rptr, col, dinv, bmu, bufB, n);
    k_mm_heads<<<gmm, 256, 0, stream>>>(bufB, Wcat, bmu, bls, mu, ls, n);
}

// Round 15
// 248.420 us; speedup vs baseline: 1.3848x; 1.0545x over previous
//
#include <hip/hip_runtime.h>
#include <hip/hip_bf16.h>
#include <cstddef>

// ---------------------------------------------------------------------------
// GCN variational encoder: N nodes, E edges, H=128 hidden, C=64 out.
// A(HW) = (AH)W lets each layer gather in the narrow domain.
// Gathers: per-VMEM-instruction packed; 128-wide gather sits at the
// COMPULSORY per-XCD first-touch floor (Poisson model: 8 XCD x 86% of the
// 25.6MB table = 177MB ~= measured 186MB) -- accepted.
// Fixed-cost shaves: prepW merged into hist, l1 grid-stride, NT stores
// (via ext_vector_type -- HIP float4 is rejected by the builtin).
// ---------------------------------------------------------------------------

typedef float v4f __attribute__((ext_vector_type(4)));
typedef float v2f __attribute__((ext_vector_type(2)));

// ---- CSR pipeline (bucket = dst>>8; requires n <= 65536) ----

// blocks [0,ntile): per-tile bucket histogram.
// blocks [ntile, ntile+nsm): M = embW @ W1 rows. blocks [ntile+nsm, +32): Wcat.
__global__ __launch_bounds__(256) void k_histprep(const int* __restrict__ dst,
                                                  int* __restrict__ hist_g, int e,
                                                  int ntile,
                                                  const float* __restrict__ embW,
                                                  const float* __restrict__ W1,
                                                  const float* __restrict__ Wmu,
                                                  const float* __restrict__ Wls,
                                                  float* __restrict__ M,
                                                  float* __restrict__ Wcat,
                                                  int V, int nsm) {
    const int tid = threadIdx.x;
    if ((int)blockIdx.x < ntile) {
        __shared__ int h[256];
        h[tid] = 0;
        __syncthreads();
        const int e0 = blockIdx.x * 4096;
        const int e1 = min(e0 + 4096, e);
        for (int j = e0 + tid; j < e1; j += 256) atomicAdd(&h[dst[j] >> 8], 1);
        __syncthreads();
        hist_g[blockIdx.x * 256 + tid] = h[tid];
    } else if ((int)blockIdx.x < ntile + nsm) {
        const int r = (blockIdx.x - ntile) * 2 + (tid >> 7);
        const int c = tid & 127;
        if (r >= V) return;
        float a0 = 0.f, a1 = 0.f;
        const float* er = embW + (size_t)r * 128;
#pragma unroll 4
        for (int k = 0; k < 128; k += 2) {
            a0 = fmaf(er[k], W1[(size_t)k * 128 + c], a0);
            a1 = fmaf(er[k + 1], W1[(size_t)(k + 1) * 128 + c], a1);
        }
        M[(size_t)r * 128 + c] = a0 + a1;
    } else {
        int i = (blockIdx.x - ntile - nsm) * 256 + tid;
        if (i < 64 * 128) {
            int k = i >> 7, c = i & 127;
            Wcat[i] = (c < 64) ? Wmu[k * 64 + c] : Wls[k * 64 + (c - 64)];
        }
    }
}

// one block per bucket: parallel scan over tiles -> tbase; total -> bsum
__global__ __launch_bounds__(256) void k_scanT(const int* __restrict__ hist_g,
                                               int* __restrict__ tbase,
                                               int* __restrict__ bsum, int ntile) {
    const int b = blockIdx.x;
    const int t = threadIdx.x;
    const int lane = t & 63, wv = t >> 6;
    __shared__ int wsum[4];
    int carry = 0;
    for (int c = 0; c < ntile; c += 256) {
        int tt = c + t;
        int v0 = (tt < ntile) ? hist_g[tt * 256 + b] : 0;
        int v = v0;
#pragma unroll
        for (int d = 1; d < 64; d <<= 1) {
            int w = __shfl_up(v, d, 64);
            if (lane >= d) v += w;
        }
        if (lane == 63) wsum[wv] = v;
        __syncthreads();
        int woff = 0;
        for (int w = 0; w < wv; ++w) woff += wsum[w];
        int tot = wsum[0] + wsum[1] + wsum[2] + wsum[3];
        if (tt < ntile) tbase[tt * 256 + b] = carry + woff + v - v0;
        carry += tot;
        __syncthreads();
    }
    if (t == 0) bsum[b] = carry;
}

// single block: exclusive scan bsum[256] -> boff[257]
__global__ __launch_bounds__(256) void k_bscan2(const int* __restrict__ bsum,
                                                int* __restrict__ boff) {
    __shared__ int wsum[4];
    const int t = threadIdx.x;
    const int lane = t & 63, wv = t >> 6;
    int v0 = bsum[t];
    int v = v0;
#pragma unroll
    for (int d = 1; d < 64; d <<= 1) {
        int w = __shfl_up(v, d, 64);
        if (lane >= d) v += w;
    }
    if (lane == 63) wsum[wv] = v;
    __syncthreads();
    int woff = 0;
    for (int w = 0; w < wv; ++w) woff += wsum[w];
    int excl = woff + v - v0;
    boff[t] = excl;
    if (t == 255) boff[256] = excl + v0;
}

// single-pass scatter: packed (dlocal<<16 | src) at boff[b]+tbase[tile][b]+rank
__global__ __launch_bounds__(256) void k_binA3(const int* __restrict__ src,
                                               const int* __restrict__ dst,
                                               const int* __restrict__ boff,
                                               const int* __restrict__ tbase,
                                               int* __restrict__ packed, int e) {
    __shared__ int hist[256];
    __shared__ int base[256];
    const int tid = threadIdx.x;
    const int e0 = blockIdx.x * 4096;
    const int e1 = min(e0 + 4096, e);
    hist[tid] = 0;
    base[tid] = boff[tid] + tbase[blockIdx.x * 256 + tid];
    __syncthreads();
    for (int j = e0 + tid; j < e1; j += 256) {
        int d = dst[j];
        int b = d >> 8;
        int r = atomicAdd(&hist[b], 1);
        packed[base[b] + r] = ((d & 255) << 16) | src[j];
    }
}

// per bucket (1024 threads): node hist + scan -> rptr/dinv/xd; LDS sort -> col
#define BCAP 6144
__global__ __launch_bounds__(1024) void k_binB2(const int* __restrict__ packed,
                                                const int* __restrict__ boff,
                                                const int* __restrict__ x,
                                                int* __restrict__ rptr,
                                                float* __restrict__ dinv,
                                                int2* __restrict__ xd,
                                                int* __restrict__ col,
                                                int n) {
    __shared__ int hist[256];
    __shared__ int cur[256];
    __shared__ int wsum[4];
    __shared__ int buf[BCAP];
    const int tid = threadIdx.x;
    const int node0 = blockIdx.x << 8;
    const int node1 = min(node0 + 256, n);
    const int ebeg = boff[blockIdx.x];
    const int eend = boff[blockIdx.x + 1];
    const int cnt = eend - ebeg;

    if (tid < 256) hist[tid] = 0;
    __syncthreads();
    for (int j = tid; j < cnt; j += 1024) atomicAdd(&hist[packed[ebeg + j] >> 16], 1);
    __syncthreads();

    int deg = 0, v = 0;
    if (tid < 256) {
        const int lane = tid & 63, wv = tid >> 6;
        deg = hist[tid];
        v = deg;
#pragma unroll
        for (int d = 1; d < 64; d <<= 1) {
            int w = __shfl_up(v, d, 64);
            if (lane >= d) v += w;
        }
        if (lane == 63) wsum[wv] = v;
    }
    __syncthreads();
    if (tid < 256) {
        const int wv = tid >> 6;
        int woff = 0;
        for (int w = 0; w < wv; ++w) woff += wsum[w];
        const int excl = woff + v - deg;
        cur[tid] = excl;
        const int node = node0 + tid;
        if (node < node1) {
            rptr[node] = ebeg + excl;
            float dv = 1.0f / sqrtf((float)(deg + 1));
            dinv[node] = dv;
            xd[node] = make_int2(x[node], __float_as_int(dv));
        }
        if (node1 == n && tid == 0) rptr[n] = eend;
    }
    __syncthreads();

    if (cnt <= BCAP) {
        for (int j = tid; j < cnt; j += 1024) {
            int p = packed[ebeg + j];
            int pos = atomicAdd(&cur[p >> 16], 1);
            buf[pos] = p & 0xffff;
        }
        __syncthreads();
        for (int j = tid; j < cnt; j += 1024) col[ebeg + j] = buf[j];
    } else {
        for (int j = tid; j < cnt; j += 1024) {
            int p = packed[ebeg + j];
            int pos = atomicAdd(&cur[p >> 16], 1);
            col[ebeg + pos] = p & 0xffff;
        }
    }
}

// layer-1 gather (grid-stride): M table in LDS staged once per block;
// per edge read packed xd[s]={x,dinv} and accumulate dinv * M[x].
__global__ __launch_bounds__(256) void k_gather_l1(const float* __restrict__ M,
                                                   const int* __restrict__ rptr,
                                                   const int* __restrict__ col,
                                                   const int2* __restrict__ xd,
                                                   const float* __restrict__ b,
                                                   float* __restrict__ out,
                                                   int n, int V) {
    __shared__ float sh[32 * 128];
    for (int f = threadIdx.x; f < V * 32; f += 256)
        ((float4*)sh)[f] = ((const float4*)M)[f];
    __syncthreads();

    const int wave = threadIdx.x >> 6;
    const int lane = threadIdx.x & 63;
    const int lo = 2 * lane;
    const int stride = gridDim.x * 4;

    for (int node = blockIdx.x * 4 + wave; node < n; node += stride) {
        const int beg = rptr[node], end = rptr[node + 1];
        int j = beg;
        float ax0 = 0.f, ay0 = 0.f, ax1 = 0.f, ay1 = 0.f;
        if (end - beg >= 8) {
            int s[8];
#pragma unroll
            for (int u = 0; u < 8; ++u) s[u] = col[j + u];
            j += 8;
            while (true) {
                int2 p[8];
#pragma unroll
                for (int u = 0; u < 8; ++u) p[u] = xd[s[u]];
                const bool more = (j + 8 <= end);
                int sn[8];
                if (more) {
#pragma unroll
                    for (int u = 0; u < 8; ++u) sn[u] = col[j + u];
                }
#pragma unroll
                for (int u = 0; u < 8; ++u) {
                    float dv = __int_as_float(p[u].y);
                    float2 vv = *(const float2*)&sh[p[u].x * 128 + lo];
                    if (u & 1) { ax1 = fmaf(dv, vv.x, ax1); ay1 = fmaf(dv, vv.y, ay1); }
                    else       { ax0 = fmaf(dv, vv.x, ax0); ay0 = fmaf(dv, vv.y, ay0); }
                }
                if (!more) break;
#pragma unroll
                for (int u = 0; u < 8; ++u) s[u] = sn[u];
                j += 8;
            }
        }
        for (; j < end; ++j) {
            int2 p = xd[col[j]];
            float dv = __int_as_float(p.y);
            float2 vv = *(const float2*)&sh[p.x * 128 + lo];
            ax0 = fmaf(dv, vv.x, ax0); ay0 = fmaf(dv, vv.y, ay0);
        }
        int2 pn = xd[node];
        float dn = __int_as_float(pn.y);
        float2 sv = *(const float2*)&sh[pn.x * 128 + lo];
        float2 bb = ((const float2*)b)[lane];
        v2f o = {(ax0 + ax1 + dn * sv.x) * dn + bb.x,
                 (ay0 + ay1 + dn * sv.y) * dn + bb.y};
        __builtin_nontemporal_store(o, (v2f*)out + (size_t)node * 64 + lane);
    }
}

// out[r][c] = dinv[r] * sum_k act(in[r][k]) * W[k][c]
// BM=128, KC=32; A-tile register-prefetched across chunks.
template <int K, int COUT, bool RELU>
__global__ __launch_bounds__(256) void k_matmul(const float* __restrict__ in,
                                                const float* __restrict__ W,
                                                const float* __restrict__ dinv,
                                                float* __restrict__ out, int n) {
    constexpr int BM = 128, KC = 32, LDI = KC + 4;
    constexpr int CT = COUT / 16;
    __shared__ float sIn[BM * LDI];
    __shared__ float sW[KC * COUT];

    const int tid = threadIdx.x;
    const int row0 = blockIdx.x * BM;
    const int tc = tid & 15;
    const int tr = tid >> 4;

    float acc[8][CT];
#pragma unroll
    for (int j = 0; j < 8; ++j)
#pragma unroll
        for (int c = 0; c < CT; ++c) acc[j][c] = 0.f;

    const int sr = tid >> 3;
    const int sk = (tid & 7) * 4;

    float4 pf[4];
#pragma unroll
    for (int p = 0; p < 4; ++p) {
        int gr = row0 + p * 32 + sr;
        pf[p] = (gr < n) ? *(const float4*)&in[(size_t)gr * K + sk]
                         : float4{0.f, 0.f, 0.f, 0.f};
    }

    for (int kc = 0; kc < K; kc += KC) {
#pragma unroll
        for (int p = 0; p < 4; ++p) {
            float4 v = pf[p];
            if (RELU) {
                v.x = fmaxf(v.x, 0.f); v.y = fmaxf(v.y, 0.f);
                v.z = fmaxf(v.z, 0.f); v.w = fmaxf(v.w, 0.f);
            }
            *(float4*)&sIn[(p * 32 + sr) * LDI + sk] = v;
        }
        for (int f4 = tid; f4 < KC * COUT / 4; f4 += 256)
            *(float4*)&sW[f4 * 4] = *(const float4*)&W[(size_t)kc * COUT + f4 * 4];
        __syncthreads();

        if (kc + KC < K) {
#pragma unroll
            for (int p = 0; p < 4; ++p) {
                int gr = row0 + p * 32 + sr;
                pf[p] = (gr < n) ? *(const float4*)&in[(size_t)gr * K + kc + KC + sk]
                                 : float4{0.f, 0.f, 0.f, 0.f};
            }
        }

        for (int kk = 0; kk < KC; kk += 4) {
            float4 a[8];
#pragma unroll
            for (int j = 0; j < 8; ++j)
                a[j] = *(const float4*)&sIn[(tr * 8 + j) * LDI + kk];
#pragma unroll
            for (int t = 0; t < 4; ++t) {
                float4 w0 = *(const float4*)&sW[(kk + t) * COUT + tc * 4];
                float4 w1;
                if constexpr (CT == 8)
                    w1 = *(const float4*)&sW[(kk + t) * COUT + COUT / 2 + tc * 4];
#pragma unroll
                for (int j = 0; j < 8; ++j) {
                    float av = (t == 0) ? a[j].x : (t == 1) ? a[j].y
                             : (t == 2) ? a[j].z : a[j].w;
                    acc[j][0] = fmaf(av, w0.x, acc[j][0]);
                    acc[j][1] = fmaf(av, w0.y, acc[j][1]);
                    acc[j][2] = fmaf(av, w0.z, acc[j][2]);
                    acc[j][3] = fmaf(av, w0.w, acc[j][3]);
                    if constexpr (CT == 8) {
                        acc[j][4] = fmaf(av, w1.x, acc[j][4]);
                        acc[j][5] = fmaf(av, w1.y, acc[j][5]);
                        acc[j][6] = fmaf(av, w1.z, acc[j][6]);
                        acc[j][7] = fmaf(av, w1.w, acc[j][7]);
                    }
                }
            }
        }
        __syncthreads();
    }

#pragma unroll
    for (int j = 0; j < 8; ++j) {
        int gr = row0 + tr * 8 + j;
        if (gr < n) {
            float dv = dinv[gr];
            float4 o0 = {acc[j][0] * dv, acc[j][1] * dv, acc[j][2] * dv, acc[j][3] * dv};
            *(float4*)&out[(size_t)gr * COUT + tc * 4] = o0;
            if constexpr (CT == 8) {
                float4 o1 = {acc[j][4] * dv, acc[j][5] * dv, acc[j][6] * dv, acc[j][7] * dv};
                *(float4*)&out[(size_t)gr * COUT + COUT / 2 + tc * 4] = o1;
            }
        }
    }
}

// heads matmul: out = g3 (N x 64) @ Wcat (64 x 128) + [bmu|bls] -> mu, ls
__global__ __launch_bounds__(256) void k_mm_heads(const float* __restrict__ in,
                                                  const float* __restrict__ W,
                                                  const float* __restrict__ bmu,
                                                  const float* __restrict__ bls,
                                                  float* __restrict__ mu,
                                                  float* __restrict__ ls, int n) {
    constexpr int BM = 128, KC = 32, LDI = KC + 4, K = 64, COUT = 128;
    __shared__ float sIn[BM * LDI];
    __shared__ float sW[KC * COUT];

    const int tid = threadIdx.x;
    const int row0 = blockIdx.x * BM;
    const int tc = tid & 15;
    const int tr = tid >> 4;

    float acc[8][8];
#pragma unroll
    for (int j = 0; j < 8; ++j)
#pragma unroll
        for (int c = 0; c < 8; ++c) acc[j][c] = 0.f;

    const int sr = tid >> 3;
    const int sk = (tid & 7) * 4;

    float4 pf[4];
#pragma unroll
    for (int p = 0; p < 4; ++p) {
        int gr = row0 + p * 32 + sr;
        pf[p] = (gr < n) ? *(const float4*)&in[(size_t)gr * K + sk]
                         : float4{0.f, 0.f, 0.f, 0.f};
    }

    for (int kc = 0; kc < K; kc += KC) {
#pragma unroll
        for (int p = 0; p < 4; ++p)
            *(float4*)&sIn[(p * 32 + sr) * LDI + sk] = pf[p];
        for (int f4 = tid; f4 < KC * COUT / 4; f4 += 256)
            *(float4*)&sW[f4 * 4] = *(const float4*)&W[(size_t)kc * COUT + f4 * 4];
        __syncthreads();

        if (kc + KC < K) {
#pragma unroll
            for (int p = 0; p < 4; ++p) {
                int gr = row0 + p * 32 + sr;
                pf[p] = (gr < n) ? *(const float4*)&in[(size_t)gr * K + kc + KC + sk]
                                 : float4{0.f, 0.f, 0.f, 0.f};
            }
        }

        for (int kk = 0; kk < KC; kk += 4) {
            float4 a[8];
#pragma unroll
            for (int j = 0; j < 8; ++j)
                a[j] = *(const float4*)&sIn[(tr * 8 + j) * LDI + kk];
#pragma unroll
            for (int t = 0; t < 4; ++t) {
                float4 w0 = *(const float4*)&sW[(kk + t) * COUT + tc * 4];
                float4 w1 = *(const float4*)&sW[(kk + t) * COUT + 64 + tc * 4];
#pragma unroll
                for (int j = 0; j < 8; ++j) {
                    float av = (t == 0) ? a[j].x : (t == 1) ? a[j].y
                             : (t == 2) ? a[j].z : a[j].w;
                    acc[j][0] = fmaf(av, w0.x, acc[j][0]);
                    acc[j][1] = fmaf(av, w0.y, acc[j][1]);
                    acc[j][2] = fmaf(av, w0.z, acc[j][2]);
                    acc[j][3] = fmaf(av, w0.w, acc[j][3]);
                    acc[j][4] = fmaf(av, w1.x, acc[j][4]);
                    acc[j][5] = fmaf(av, w1.y, acc[j][5]);
                    acc[j][6] = fmaf(av, w1.z, acc[j][6]);
                    acc[j][7] = fmaf(av, w1.w, acc[j][7]);
                }
            }
        }
        __syncthreads();
    }

    float4 bm = ((const float4*)bmu)[tc];
    float4 bl = ((const float4*)bls)[tc];
#pragma unroll
    for (int j = 0; j < 8; ++j) {
        int gr = row0 + tr * 8 + j;
        if (gr < n) {
            float4 o0 = {acc[j][0] + bm.x, acc[j][1] + bm.y, acc[j][2] + bm.z, acc[j][3] + bm.w};
            float4 o1 = {acc[j][4] + bl.x, acc[j][5] + bl.y, acc[j][6] + bl.z, acc[j][7] + bl.w};
            *(float4*)&mu[(size_t)gr * 64 + tc * 4] = o0;
            *(float4*)&ls[(size_t)gr * 64 + tc * 4] = o1;
        }
    }
}

// 128-wide packed gather (layer 2): 32 lanes x float4 = one full row ->
// 2 edges per wave-instruction; 16 edges/iteration, masked. shfl_xor(32).
__global__ __launch_bounds__(256) void k_gather128p(const float* __restrict__ tab,
                                                    const int* __restrict__ rptr,
                                                    const int* __restrict__ col,
                                                    const float* __restrict__ dinv,
                                                    const float* __restrict__ b,
                                                    float* __restrict__ out, int n) {
    const int wave = threadIdx.x >> 6;
    const int lane = threadIdx.x & 63;
    const int g = lane >> 5;
    const int q = lane & 31;
    const int node = blockIdx.x * 4 + wave;
    if (node >= n) return;
    const int beg = rptr[node], end = rptr[node + 1];

    float4 acc = {0.f, 0.f, 0.f, 0.f};
    int j = beg;
    if (j < end) {
        int s[8]; bool val[8];
#pragma unroll
        for (int u = 0; u < 8; ++u) {
            int ei = j + 2 * u + g;
            val[u] = ei < end;
            s[u] = val[u] ? col[ei] : node;
        }
        j += 16;
        while (true) {
            float4 v[8];
#pragma unroll
            for (int u = 0; u < 8; ++u)
                v[u] = *(const float4*)&tab[(size_t)s[u] * 128 + q * 4];
            const bool more = j < end;
            int sn[8]; bool vn[8];
            if (more) {
#pragma unroll
                for (int u = 0; u < 8; ++u) {
                    int ei = j + 2 * u + g;
                    vn[u] = ei < end;
                    sn[u] = vn[u] ? col[ei] : node;
                }
            }
#pragma unroll
            for (int u = 0; u < 8; ++u) {
                if (val[u]) {
                    acc.x += v[u].x; acc.y += v[u].y;
                    acc.z += v[u].z; acc.w += v[u].w;
                }
            }
            if (!more) break;
#pragma unroll
            for (int u = 0; u < 8; ++u) { s[u] = sn[u]; val[u] = vn[u]; }
            j += 16;
        }
    }
    acc.x += __shfl_xor(acc.x, 32, 64); acc.y += __shfl_xor(acc.y, 32, 64);
    acc.z += __shfl_xor(acc.z, 32, 64); acc.w += __shfl_xor(acc.w, 32, 64);

    if (g == 0) {
        float4 self = *(const float4*)&tab[(size_t)node * 128 + q * 4];
        float dn = dinv[node];
        float4 bb = ((const float4*)b)[q];
        v4f o = {(acc.x + self.x) * dn + bb.x, (acc.y + self.y) * dn + bb.y,
                 (acc.z + self.z) * dn + bb.z, (acc.w + self.w) * dn + bb.w};
        __builtin_nontemporal_store(o, (v4f*)&out[(size_t)node * 128 + q * 4]);
    }
}

// 64-wide packed gather: 16 lanes x float4 = one full row -> 4 edges/instr.
// MODE 1: out = dn*relu(o + b)  (layer 3);  MODE 2: out = o  (head pre-gather)
template <int MODE>
__global__ __launch_bounds__(256) void k_gather64p(const float* __restrict__ tab,
                                                   const int* __restrict__ rptr,
                                                   const int* __restrict__ col,
                                                   const float* __restrict__ dinv,
                                                   const float* __restrict__ b,
                                                   float* __restrict__ out, int n) {
    const int wave = threadIdx.x >> 6;
    const int lane = threadIdx.x & 63;
    const int g = lane >> 4;
    const int q = lane & 15;
    const int node = blockIdx.x * 4 + wave;
    if (node >= n) return;
    const int beg = rptr[node], end = rptr[node + 1];

    float4 acc = {0.f, 0.f, 0.f, 0.f};
    int j = beg;
    if (j < end) {
        int s[4]; bool val[4];
#pragma unroll
        for (int u = 0; u < 4; ++u) {
            int ei = j + 4 * u + g;
            val[u] = ei < end;
            s[u] = val[u] ? col[ei] : node;
        }
        j += 16;
        while (true) {
            float4 v[4];
#pragma unroll
            for (int u = 0; u < 4; ++u)
                v[u] = *(const float4*)&tab[(size_t)s[u] * 64 + q * 4];
            const bool more = j < end;
            int sn[4]; bool vn[4];
            if (more) {
#pragma unroll
                for (int u = 0; u < 4; ++u) {
                    int ei = j + 4 * u + g;
                    vn[u] = ei < end;
                    sn[u] = vn[u] ? col[ei] : node;
                }
            }
#pragma unroll
            for (int u = 0; u < 4; ++u) {
                if (val[u]) {
                    acc.x += v[u].x; acc.y += v[u].y;
                    acc.z += v[u].z; acc.w += v[u].w;
                }
            }
            if (!more) break;
#pragma unroll
            for (int u = 0; u < 4; ++u) { s[u] = sn[u]; val[u] = vn[u]; }
            j += 16;
        }
    }
    acc.x += __shfl_xor(acc.x, 16, 64); acc.y += __shfl_xor(acc.y, 16, 64);
    acc.z += __shfl_xor(acc.z, 16, 64); acc.w += __shfl_xor(acc.w, 16, 64);
    acc.x += __shfl_xor(acc.x, 32, 64); acc.y += __shfl_xor(acc.y, 32, 64);
    acc.z += __shfl_xor(acc.z, 32, 64); acc.w += __shfl_xor(acc.w, 32, 64);

    if (g == 0) {
        float4 self = *(const float4*)&tab[(size_t)node * 64 + q * 4];
        float dn = dinv[node];
        v4f o = {(acc.x + self.x) * dn, (acc.y + self.y) * dn,
                 (acc.z + self.z) * dn, (acc.w + self.w) * dn};
        if constexpr (MODE == 1) {
            float4 bb = ((const float4*)b)[q];
            o.x = fmaxf(o.x + bb.x, 0.f) * dn;
            o.y = fmaxf(o.y + bb.y, 0.f) * dn;
            o.z = fmaxf(o.z + bb.z, 0.f) * dn;
            o.w = fmaxf(o.w + bb.w, 0.f) * dn;
        }
        __builtin_nontemporal_store(o, (v4f*)&out[(size_t)node * 64 + q * 4]);
    }
}

extern "C" void kernel_launch(void* const* d_in, const int* in_sizes, int n_in,
                              void* d_out, int out_size, void* d_ws, size_t ws_size,
                              hipStream_t stream) {
    const int*   x    = (const int*)d_in[0];
    const int*   ei   = (const int*)d_in[1];
    const float* embW = (const float*)d_in[2];
    const float* W1   = (const float*)d_in[3];
    const float* b1   = (const float*)d_in[4];
    const float* W2   = (const float*)d_in[5];
    const float* b2   = (const float*)d_in[6];
    const float* W3   = (const float*)d_in[7];
    const float* b3   = (const float*)d_in[8];
    const float* Wmu  = (const float*)d_in[9];
    const float* bmu  = (const float*)d_in[10];
    const float* Wls  = (const float*)d_in[11];
    const float* bls  = (const float*)d_in[12];

    const int n = in_sizes[0];
    const int e = in_sizes[1] / 2;
    const int V = in_sizes[2] / 128;
    const int* src = ei;
    const int* dst = ei + e;

    char* w = (char*)d_ws;
    auto alloc = [&](size_t bytes) {
        char* p = w;
        w += (bytes + 255) & ~(size_t)255;
        return p;
    };
    float* bufA = (float*)alloc((size_t)n * 128 * 4);
    float* bufB = (float*)alloc((size_t)n * 128 * 4);
    float* hW   = (float*)alloc((size_t)n * 128 * 4);
    int*   rptr = (int*)alloc((size_t)(n + 1) * 4);
    int*   col  = (int*)alloc((size_t)e * 4);
    int*   pck  = (int*)alloc((size_t)e * 4);
    float* dinv = (float*)alloc((size_t)n * 4);
    int2*  xd   = (int2*)alloc((size_t)n * 8);
    float* Wcat = (float*)alloc((size_t)64 * 128 * 4);
    float* Msm  = (float*)alloc((size_t)32 * 128 * 4);
    int*   boff = (int*)alloc((size_t)257 * 4);
    int*   bsum = (int*)alloc((size_t)256 * 4);

    const int ntile = (e + 4095) / 4096;
    const int nbuck = (n + 255) / 256;
    int* hist_g = (int*)alloc((size_t)ntile * 256 * 4);
    int* tbase  = (int*)alloc((size_t)ntile * 256 * 4);

    const int nsm = (V + 1) / 2;

    // ---- atomic-free CSR build + weight prep (fused into one wave) ----
    k_histprep<<<ntile + nsm + 32, 256, 0, stream>>>(dst, hist_g, e, ntile,
                                                     embW, W1, Wmu, Wls,
                                                     Msm, Wcat, V, nsm);
    k_scanT <<<256, 256, 0, stream>>>(hist_g, tbase, bsum, ntile);
    k_bscan2<<<1, 256, 0, stream>>>(bsum, boff);
    k_binA3 <<<ntile, 256, 0, stream>>>(src, dst, boff, tbase, pck, e);
    k_binB2 <<<nbuck, 1024, 0, stream>>>(pck, boff, x, rptr, dinv, xd, col, n);

    const int gmm = (n + 127) / 128;
    const int ggt = (n + 3) / 4;
    float* mu = (float*)d_out;
    float* ls = (float*)d_out + (size_t)n * 64;

    // layer 1: 28-row LDS-table gather (grid-stride, LDS staged once/block)
    k_gather_l1<<<2048, 256, 0, stream>>>(Msm, rptr, col, xd, b1, bufA, n, V);
    // layer 2: matmul (relu on load) + packed 128-wide gather
    k_matmul<128, 128, true><<<gmm, 256, 0, stream>>>(bufA, W2, dinv, hW, n);
    k_gather128p<<<ggt, 256, 0, stream>>>(hW, rptr, col, dinv, b2, bufB, n);
    // layer 3: matmul 128->64 + packed 64-wide gather, out = dinv*relu(conv3)
    k_matmul<128, 64, true><<<gmm, 256, 0, stream>>>(bufB, W3, dinv, hW, n);
    k_gather64p<1><<<ggt, 256, 0, stream>>>(hW, rptr, col, dinv, b3, bufA, n);
    // heads: g3 = A*(dinv*relu(conv3)) packed gather, then 64->128 matmul
    k_gather64p<2><<<ggt, 256, 0, stream>>>(bufA, rptr, col, dinv, bmu, bufB, n);
    k_mm_heads<<<gmm, 256, 0, stream>>>(bufB, Wcat, bmu, bls, mu, ls, n);
}